// Round 11
// baseline (417.363 us; speedup 1.0000x reference)
//
#include <hip/hip_runtime.h>
#include <math.h>

typedef unsigned short u16;
typedef __attribute__((ext_vector_type(4))) float f32x4;
typedef __attribute__((ext_vector_type(8))) short bf16x8;
typedef __attribute__((ext_vector_type(4))) unsigned short u16x4;
typedef __attribute__((ext_vector_type(8))) unsigned short u16x8;

#define DEVI static __device__ __forceinline__

DEVI float b2f(u16 u){ union{float f; unsigned i;} v; v.i = ((unsigned)u)<<16; return v.f; }
DEVI u16 f2b(float f){ union{float f; unsigned i;} v; v.f=f;
  unsigned r = v.i + 0x7fffu + ((v.i>>16)&1u); return (u16)(r>>16); }

DEVI void gload_lds16(const void* g, void* l){
  __builtin_amdgcn_global_load_lds((const __attribute__((address_space(1))) void*)g,
                                   (__attribute__((address_space(3))) void*)l, 16, 0, 0);
}

// LDS-only barrier: waits DS ops, does NOT drain vmcnt (keeps prefetch in flight)
DEVI void lds_bar(){ asm volatile("s_waitcnt lgkmcnt(0)\n\ts_barrier" ::: "memory"); }

DEVI f32x4 vmax4(f32x4 a, f32x4 b){
  f32x4 r; r[0]=fmaxf(a[0],b[0]); r[1]=fmaxf(a[1],b[1]);
  r[2]=fmaxf(a[2],b[2]); r[3]=fmaxf(a[3],b[3]); return r;
}

// ---------------------------------------------------------------------------
// Merged prologue: blocks [0,2048): W1/W2 -> bf16 [c][k]; blocks [2048,2176):
// mu/nu + base-2 logs (2 batches per 256-thread block).
__global__ void prologue_k(const float* __restrict__ W1, const float* __restrict__ W2,
                           u16* __restrict__ W1T, u16* __restrict__ W2T,
                           const float* __restrict__ mask_q, const float* __restrict__ mask_r,
                           float* __restrict__ lmu2, float* __restrict__ lnu2,
                           float* __restrict__ mu, float* __restrict__ nu){
  const int blk = blockIdx.x;
  if (blk < 2048){
    const float* W = (blk<1024)? W1 : W2;
    u16* Wt = (blk<1024)? W1T : W2T;
    int id = (blk&1023)*256 + threadIdx.x;
    int k = id>>9, c = id&511;
    Wt[c*512 + k] = f2b(W[id]);
  } else {
    __shared__ float red[2][4];
    const int h = threadIdx.x>>7, t = threadIdx.x&127;
    const int b = (blk-2048)*2 + h;
    float mq = mask_q[b*128+t], mr = mask_r[b*128+t];
    float s1 = mq, s2 = mr;
    #pragma unroll
    for (int off=1;off<64;off<<=1){ s1 += __shfl_xor(s1,off); s2 += __shfl_xor(s2,off); }
    if ((t&63)==0){ red[h][(t>>6)&1] = s1; red[h][2+((t>>6)&1)] = s2; }
    __syncthreads();
    float sumq = red[h][0]+red[h][1], sumr = red[h][2]+red[h][3];
    float muv = mq/(sumq+1e-8f), nuv = mr/(sumr+1e-8f);
    lmu2[b*128+t] = __log2f(fmaxf(muv,1e-8f));
    lnu2[b*128+t] = __log2f(fmaxf(nuv,1e-8f));
    mu[b*128+t] = muv;
    nu[b*128+t] = nuv;
  }
}

// ---------------------------------------------------------------------------
// OUT[r][c] = act(sum_k X[r][k]*W[k][c] + bias[c]); Wt bf16 [c][k].
// AF32: A-tile reg-staged from f32 sources. NORM: per-cb row-norm partials
// written non-atomically to NP4[cb][row]. Epilogue via LDS transpose.
template<int ACT, int NORM, int AF32>
__global__ __launch_bounds__(256) void gemm_k(const u16* __restrict__ X,
    const float* __restrict__ Xf1, const float* __restrict__ Xf2,
    const u16* __restrict__ Wt, const float* __restrict__ bias, u16* __restrict__ OUT,
    float* __restrict__ NP4){
  __shared__ __align__(16) u16 smem[17920];
  u16* sA = smem;
  u16* sB = smem + 8192;
  const int tid = threadIdx.x, wave = tid>>6, lane = tid&63;
  const int bid = (blockIdx.x&7)*256 + (blockIdx.x>>3);
  const int rblk = bid>>2, cb = (bid&3)<<7;
  const u16* Xb = AF32 ? nullptr : (X + (size_t)rblk*(128*512));
  const float* Xbf = AF32 ? (rblk<256 ? Xf1 + (size_t)rblk*65536
                                      : Xf2 + (size_t)(rblk-256)*65536) : nullptr;
  const u16* Wb = Wt + (size_t)cb*512;
  const int lrow = lane&15, lg = lane>>4, wr = wave>>1, wc = wave&1;
  f32x4 acc[4][4] = {};
  for (int s=0;s<8;s++){
    const int k0 = s<<6;
    #pragma unroll
    for (int q=0;q<4;q++){
      const int i = (wave<<2)+q;
      const int row = (i<<3) + (lane>>3);
      const int cd = (lane&7) ^ (row&7);
      if (AF32){
        const float* src = Xbf + row*512 + k0 + (cd<<3);
        const f32x4 va = *(const f32x4*)src;
        const f32x4 vb = *(const f32x4*)(src+4);
        u16x8 t;
        #pragma unroll
        for (int e=0;e<4;e++){ t[e]=f2b(va[e]); t[4+e]=f2b(vb[e]); }
        *(u16x8*)((char*)sA + i*1024 + lane*16) = t;
      } else {
        gload_lds16(Xb + row*512 + k0 + (cd<<3), sA + i*512);
      }
      gload_lds16(Wb + row*512 + k0 + (cd<<3), sB + i*512);
    }
    __syncthreads();
    #pragma unroll
    for (int kh=0;kh<2;kh++){
      bf16x8 a_[4], b_[4];
      #pragma unroll
      for (int i=0;i<4;i++){
        const int ra = (wr<<6)+(i<<4)+lrow;
        a_[i] = *(const bf16x8*)(sA + ra*64 + ((((kh<<2)+lg)^(ra&7))<<3));
        const int rb = (wc<<6)+(i<<4)+lrow;
        b_[i] = *(const bf16x8*)(sB + rb*64 + ((((kh<<2)+lg)^(rb&7))<<3));
      }
      #pragma unroll
      for (int i=0;i<4;i++)
        #pragma unroll
        for (int j=0;j<4;j++)
          acc[i][j] = __builtin_amdgcn_mfma_f32_16x16x32_bf16(a_[i], b_[j], acc[i][j], 0,0,0);
    }
    __syncthreads();
  }
  #pragma unroll
  for (int j=0;j<4;j++){
    const int colb = (wc<<6) + (j<<4) + lrow;
    const float bv = bias[cb + colb];
    #pragma unroll
    for (int i=0;i<4;i++){
      const int rowb = (wr<<6)+(i<<4)+(lg<<2);
      #pragma unroll
      for (int r=0;r<4;r++){
        float v = acc[i][j][r] + bv;
        if (ACT) v = fmaxf(v, 0.f);
        smem[(rowb+r)*140 + colb] = f2b(v);
      }
    }
  }
  __syncthreads();
  const int chunk = lane&15, rql = lane>>4;
  float ns[8];
  #pragma unroll
  for (int it=0; it<8; it++){
    const int rowb = it*16 + wave*4 + rql;
    u16x8 v8 = *(const u16x8*)(smem + rowb*140 + chunk*8);
    *(u16x8*)(OUT + (size_t)((rblk<<7)+rowb)*512 + cb + chunk*8) = v8;
    if (NORM){
      float s = 0.f;
      #pragma unroll
      for (int e=0;e<8;e++){ float f = b2f(v8[e]); s = fmaf(f,f,s); }
      s += __shfl_xor(s,1); s += __shfl_xor(s,2);
      s += __shfl_xor(s,4); s += __shfl_xor(s,8);
      ns[it] = s;
    }
  }
  if (NORM && chunk==0){
    #pragma unroll
    for (int it=0;it<8;it++)
      NP4[(size_t)(bid&3)*65536 + (rblk<<7) + it*16 + wave*4 + rql] = ns[it];
  }
}

// ---------------------------------------------------------------------------
// pdist_all: 768 blocks. [0,256): C from P; [256,512): Sq planes; [512,768): Sr.
__global__ __launch_bounds__(256) void pdist_all_k(const u16* __restrict__ PQ,
    const float* __restrict__ NP4, const float* __restrict__ cq,
    const float* __restrict__ cr, float* __restrict__ Cm,
    char* __restrict__ SQHL, char* __restrict__ SRHL){
  __shared__ __align__(16) u16 sA[8192];
  __shared__ __align__(16) u16 sB[8192];
  __shared__ float nA[128], nB[128];
  const int tid = threadIdx.x, wave = tid>>6, lane = tid&63;
  const int lrow = lane&15, lg = lane>>4, wr = wave>>1, wc = wave&1;
  const int b = blockIdx.x & 255;

  if (blockIdx.x < 256){
    if (tid < 128){
      const int row = b*128 + tid;
      nA[tid] = NP4[row] + NP4[65536+row] + NP4[131072+row] + NP4[196608+row];
    } else {
      const int row = 32768 + b*128 + (tid-128);
      nB[tid-128] = NP4[row] + NP4[65536+row] + NP4[131072+row] + NP4[196608+row];
    }
    const u16* Ab = PQ + (size_t)b*(128*512);
    const u16* Bb = PQ + (size_t)(32768 + b*128)*512;
    f32x4 acc[4][4] = {};
    for (int s=0;s<8;s++){
      const int k0 = s<<6;
      #pragma unroll
      for (int q=0;q<4;q++){
        const int i = (wave<<2)+q;
        const int row = (i<<3) + (lane>>3);
        const int cd = (lane&7) ^ (row&7);
        gload_lds16(Ab + row*512 + k0 + (cd<<3), sA + i*512);
        gload_lds16(Bb + row*512 + k0 + (cd<<3), sB + i*512);
      }
      __syncthreads();
      #pragma unroll
      for (int kh=0;kh<2;kh++){
        bf16x8 a_[4], b_[4];
        #pragma unroll
        for (int i=0;i<4;i++){
          const int ra = (wr<<6)+(i<<4)+lrow;
          a_[i] = *(const bf16x8*)(sA + ra*64 + ((((kh<<2)+lg)^(ra&7))<<3));
          const int rb = (wc<<6)+(i<<4)+lrow;
          b_[i] = *(const bf16x8*)(sB + rb*64 + ((((kh<<2)+lg)^(rb&7))<<3));
        }
        #pragma unroll
        for (int i=0;i<4;i++)
          #pragma unroll
          for (int j=0;j<4;j++)
            acc[i][j] = __builtin_amdgcn_mfma_f32_16x16x32_bf16(a_[i], b_[j], acc[i][j], 0,0,0);
      }
      __syncthreads();
    }
    #pragma unroll
    for (int j=0;j<4;j++){
      const int col = (wc<<6)+(j<<4)+lrow;
      const float nbv = nB[col];
      #pragma unroll
      for (int i=0;i<4;i++){
        const int row0 = (wr<<6)+(i<<4)+(lg<<2);
        #pragma unroll
        for (int r=0;r<4;r++){
          float n2 = nA[row0+r] + nbv - 2.0f*acc[i][j][r];
          Cm[(size_t)b*16384 + (size_t)(row0+r)*128 + col] = sqrtf(fmaxf(n2, 1e-6f));
        }
      }
    }
  } else {
    const float* Sb = ((blockIdx.x < 512)? cq : cr) + (size_t)b*65536;
    char* SHL = (blockIdx.x < 512)? SQHL : SRHL;
    f32x4 acc[4][4] = {};
    float nacc[4] = {0.f,0.f,0.f,0.f};
    for (int s=0;s<8;s++){
      const int k0 = s<<6;
      #pragma unroll
      for (int q=0;q<4;q++){
        const int i = (wave<<2)+q;
        const int row = (i<<3) + (lane>>3);
        const int cd = (lane&7) ^ (row&7);
        const float* src = Sb + row*512 + k0 + (cd<<3);
        const f32x4 va = *(const f32x4*)src;
        const f32x4 vb = *(const f32x4*)(src+4);
        u16x8 t;
        #pragma unroll
        for (int e=0;e<4;e++){ t[e]=f2b(va[e]); t[4+e]=f2b(vb[e]); }
        #pragma unroll
        for (int e=0;e<8;e++){ float fv=b2f(t[e]); nacc[q]=fmaf(fv,fv,nacc[q]); }
        *(u16x8*)((char*)sA + i*1024 + lane*16) = t;
      }
      __syncthreads();
      #pragma unroll
      for (int kh=0;kh<2;kh++){
        bf16x8 a_[4], b_[4];
        #pragma unroll
        for (int i=0;i<4;i++){
          const int ra = (wr<<6)+(i<<4)+lrow;
          a_[i] = *(const bf16x8*)(sA + ra*64 + ((((kh<<2)+lg)^(ra&7))<<3));
          const int rb = (wc<<6)+(i<<4)+lrow;
          b_[i] = *(const bf16x8*)(sA + rb*64 + ((((kh<<2)+lg)^(rb&7))<<3));
        }
        #pragma unroll
        for (int i=0;i<4;i++)
          #pragma unroll
          for (int j=0;j<4;j++)
            acc[i][j] = __builtin_amdgcn_mfma_f32_16x16x32_bf16(a_[i], b_[j], acc[i][j], 0,0,0);
      }
      __syncthreads();
    }
    #pragma unroll
    for (int q=0;q<4;q++){
      float v = nacc[q];
      v += __shfl_xor(v,1); v += __shfl_xor(v,2); v += __shfl_xor(v,4);
      if ((lane&7)==0) nA[((wave<<2)+q)*8 + (lane>>3)] = v;
    }
    __syncthreads();
    #pragma unroll
    for (int j=0;j<4;j++){
      const int col = (wc<<6)+(j<<4)+lrow;
      const float nbv = nA[col];
      #pragma unroll
      for (int i=0;i<4;i++){
        const int row0 = (wr<<6)+(i<<4)+(lg<<2);
        u16x4 hi4, lo4;
        #pragma unroll
        for (int r=0;r<4;r++){
          float n2 = nA[row0+r] + nbv - 2.0f*acc[i][j][r];
          float sv = sqrtf(fmaxf(n2, 1e-6f));
          u16 h = f2b(sv); hi4[r] = h;
          lo4[r] = f2b(sv - b2f(h));
        }
        const int sa = col*256 + ((((row0>>3)^col)&15)<<4) + ((row0&7)<<1);
        char* base = SHL + (size_t)b*65536;
        *(u16x4*)(base + sa) = hi4;
        *(u16x4*)(base + 32768 + sa) = lo4;
      }
    }
  }
}

// ---------------------------------------------------------------------------
// 5-iter FGW loop, 1024 threads/block (16 waves = 4/SIMD), base-2 log-domain
// Sinkhorn. Per-thread work halved vs 512-thr version; all prior opts kept
// (C-resident, closed-form bv, exchange transposes, Sr prefetch, lgkm bars).
// MFMA: wave w -> A-tile at=w>>1 (rows 16at..), B-tiles 4(w&1)+j.
// Sinkhorn: thread (w,l7,p8) owns row kR=8w+l7, cols [16p8,16p8+16).
__global__ __launch_bounds__(1024,1) void fgw_loop_k(
    const char* __restrict__ SQHL, const char* __restrict__ SRHL,
    const float* __restrict__ C_g,
    const float* __restrict__ MU, const float* __restrict__ NU,
    const float* __restrict__ LMU2, const float* __restrict__ LNU2,
    const float* __restrict__ log_eps,
    float* __restrict__ T_out, float* __restrict__ cost_out, float* __restrict__ sim_out)
{
  __shared__ __align__(16) char bufT[65536];   // T planes / TSr^T planes / lk exchange
  __shared__ __align__(16) char bufS[65536];   // Sr planes / Sq planes (prefetch target)
  __shared__ __align__(16) float avs[128], bvs[128], t1s[128], t2s[128];
  __shared__ __align__(16) float lus[128], lvs[128];
  __shared__ float redc[16];

  const int b = blockIdx.x, tid = threadIdx.x;
  const int w = tid>>6, lane = tid&63, l15 = lane&15, lg = lane>>4;
  const int l7 = lane&7, p8 = lane>>3;
  const int at = w>>1, par = w&1;
  const char* SqHLb = SQHL + (size_t)b*65536;
  const char* SrHLb = SRHL + (size_t)b*65536;
  const float* Cb   = C_g + (size_t)b*16384;
  const float* MUb  = MU + b*128;
  const float* NUb  = NU + b*128;

  float eps = __expf(log_eps[0]); eps = fminf(fmaxf(eps,0.01f),0.5f);
  const float rho = 0.1f/(0.1f+eps);
  const float hscale = 0.5f*1.4426950408889634f/eps;   // 0.5*log2(e)/eps

  const int kR = 8*w + l7;             // Sinkhorn row / col ownership
  const float lmu2R = LMU2[b*128+kR];
  const float lnu2C = LNU2[b*128+kR];

  const int rowA256 = (16*at + l15)*256;
  const int glo2 = lg ^ (l15 & 3);
  const int ghi2 = l15 & 12;
  const int wtail = l15*256 + ((((2*at + (lg>>1)) ^ l15)&15)<<4) + ((lg&1)<<3);

  // resident C fragments, pre-scaled: rows 16(4par+j)+l15, cols 16at+4lg..+3
  f32x4 Cf2[4];
  #pragma unroll
  for (int j=0;j<4;j++)
    Cf2[j] = -hscale * (*(const f32x4*)(Cb + (size_t)(16*(4*par+j)+l15)*128 + 16*at + 4*lg));

  f32x4 lkR[4], lkC[4];
  float luR = 0.f, lvC = 0.f;

  // initial Sr staging (later outers prefetched during Sinkhorn)
  #pragma unroll
  for (int r2=0;r2<4;r2++)
    gload_lds16(SrHLb + r2*16384 + tid*16, bufS + r2*16384 + tid*16);

  for (int outer=0; outer<5; outer++){
    // ---- P0: T planes + avs; bvs via closed form
    {
      f32x4 avp = {0.f,0.f,0.f,0.f};
      #pragma unroll
      for (int jj=0;jj<4;jj++){
        f32x4 TR;
        if (outer==0){
          const f32x4 nu4 = *(const f32x4*)(NUb + 16*p8 + 4*jj);
          TR = MUb[kR]*nu4;
        } else {
          const f32x4 lv4 = *(const f32x4*)&lvs[16*p8 + 4*jj];
          #pragma unroll
          for (int e=0;e<4;e++) TR[e] = exp2f(lkR[jj][e] + luR + lv4[e]);
        }
        u16x4 hi4, lo4;
        #pragma unroll
        for (int e=0;e<4;e++){
          u16 h = f2b(TR[e]); hi4[e] = h;
          lo4[e] = f2b(TR[e] - b2f(h));
        }
        const int sa = kR*256 + ((((2*p8+(jj>>1)) ^ (kR&15))&15)<<4) + ((jj&1)<<3);
        *(u16x4*)(bufT + sa) = hi4;
        *(u16x4*)(bufT + 32768 + sa) = lo4;
        avp += TR;
      }
      float av = avp[0]+avp[1]+avp[2]+avp[3];
      av += __shfl_xor(av,8); av += __shfl_xor(av,16); av += __shfl_xor(av,32);
      if (p8==0){
        avs[kR] = av;
        bvs[kR] = (outer==0) ? NUb[kR] : exp2f(lnu2C - 10.f*eps*lvC);
      }
    }
    __syncthreads();   // drains Sr staging/prefetch + T planes + avs/bvs

    // ---- P1: t2 from Sr planes + bvs; phase A MFMA
    {
      const int p = 8*w + p8, sub = l7;     // row p, granules 2*sub..2*sub+1
      float s2 = 0.f;
      #pragma unroll
      for (int gg=0; gg<2; gg++){
        const int g = 2*sub+gg;
        const int off = p*256 + (((g ^ (p&15))&15)<<4);
        const u16x8 h8 = *(const u16x8*)(bufS + off);
        const u16x8 l8 = *(const u16x8*)(bufS + 32768 + off);
        const f32x4 bva = *(const f32x4*)&bvs[8*g];
        const f32x4 bvb = *(const f32x4*)&bvs[8*g+4];
        #pragma unroll
        for (int e=0;e<4;e++){
          float x = b2f(h8[e]) + b2f(l8[e]);
          s2 = fmaf(bva[e], x*x, s2);
          float y2 = b2f(h8[4+e]) + b2f(l8[4+e]);
          s2 = fmaf(bvb[e], y2*y2, s2);
        }
      }
      s2 += __shfl_xor(s2,1); s2 += __shfl_xor(s2,2); s2 += __shfl_xor(s2,4);
      if (sub==0) t2s[p] = s2;
    }
    f32x4 acc1[4] = {};
    #pragma unroll
    for (int qt=0;qt<4;qt++){
      const int colOff = (((4*qt) ^ ghi2) | glo2) << 4;
      const bf16x8 ahi = *(const bf16x8*)(bufT + rowA256 + colOff);
      const bf16x8 alo = *(const bf16x8*)(bufT + 32768 + rowA256 + colOff);
      #pragma unroll
      for (int j=0;j<4;j++){
        const int boff = (4*par+j)*4096 + l15*256 + colOff;
        const bf16x8 bhi = *(const bf16x8*)(bufS + boff);
        const bf16x8 blo = *(const bf16x8*)(bufS + 32768 + boff);
        acc1[j] = __builtin_amdgcn_mfma_f32_16x16x32_bf16(ahi, bhi, acc1[j], 0,0,0);
        acc1[j] = __builtin_amdgcn_mfma_f32_16x16x32_bf16(ahi, blo, acc1[j], 0,0,0);
        acc1[j] = __builtin_amdgcn_mfma_f32_16x16x32_bf16(alo, bhi, acc1[j], 0,0,0);
      }
    }
    __syncthreads();   // E

    // ---- P2: stage Sq; write TSr^T planes
    #pragma unroll
    for (int r2=0;r2<4;r2++)
      gload_lds16(SqHLb + r2*16384 + tid*16, bufS + r2*16384 + tid*16);
    #pragma unroll
    for (int j=0;j<4;j++){
      u16x4 hi4, lo4;
      #pragma unroll
      for (int r=0;r<4;r++){
        u16 h = f2b(acc1[j][r]); hi4[r] = h;
        lo4[r] = f2b(acc1[j][r] - b2f(h));
      }
      const int sa = (4*par+j)*4096 + wtail;
      *(u16x4*)(bufT + sa) = hi4;
      *(u16x4*)(bufT + 32768 + sa) = lo4;
    }
    __syncthreads();   // G: drains Sq staging + TSr^T planes

    // ---- P3: t1 from Sq planes + avs; phase B MFMA
    {
      const int p = 8*w + p8, sub = l7;
      float s1 = 0.f;
      #pragma unroll
      for (int gg=0; gg<2; gg++){
        const int g = 2*sub+gg;
        const int off = p*256 + (((g ^ (p&15))&15)<<4);
        const u16x8 h8 = *(const u16x8*)(bufS + off);
        const u16x8 l8 = *(const u16x8*)(bufS + 32768 + off);
        const f32x4 ava = *(const f32x4*)&avs[8*g];
        const f32x4 avb = *(const f32x4*)&avs[8*g+4];
        #pragma unroll
        for (int e=0;e<4;e++){
          float x = b2f(h8[e]) + b2f(l8[e]);
          s1 = fmaf(ava[e], x*x, s1);
          float y2 = b2f(h8[4+e]) + b2f(l8[4+e]);
          s1 = fmaf(avb[e], y2*y2, s1);
        }
      }
      s1 += __shfl_xor(s1,1); s1 += __shfl_xor(s1,2); s1 += __shfl_xor(s1,4);
      if (sub==0) t1s[p] = s1;
    }
    f32x4 acc2[4] = {};
    #pragma unroll
    for (int qt=0;qt<4;qt++){
      const int colOff = (((4*qt) ^ ghi2) | glo2) << 4;
      const bf16x8 ahi = *(const bf16x8*)(bufT + rowA256 + colOff);
      const bf16x8 alo = *(const bf16x8*)(bufT + 32768 + rowA256 + colOff);
      #pragma unroll
      for (int j=0;j<4;j++){
        const int boff = (4*par+j)*4096 + l15*256 + colOff;
        const bf16x8 bhi = *(const bf16x8*)(bufS + boff);
        const bf16x8 blo = *(const bf16x8*)(bufS + 32768 + boff);
        acc2[j] = __builtin_amdgcn_mfma_f32_16x16x32_bf16(ahi, bhi, acc2[j], 0,0,0);
        acc2[j] = __builtin_amdgcn_mfma_f32_16x16x32_bf16(ahi, blo, acc2[j], 0,0,0);
        acc2[j] = __builtin_amdgcn_mfma_f32_16x16x32_bf16(alo, bhi, acc2[j], 0,0,0);
      }
    }
    __syncthreads();   // I: phase-B reads done; bufS free

    // ---- P4: prefetch next Sr (hidden under Sinkhorn); lk build + exchange
    if (outer<4){
      #pragma unroll
      for (int r2=0;r2<4;r2++)
        gload_lds16(SrHLb + r2*16384 + tid*16, bufS + r2*16384 + tid*16);
    }
    f32x4 lkf[4];
    {
      const f32x4 t24 = *(const f32x4*)&t2s[16*at + 4*lg];
      #pragma unroll
      for (int j=0;j<4;j++){
        const float t1v = t1s[16*(4*par+j)+l15];
        lkf[j] = Cf2[j] + hscale*(2.0f*acc2[j] - t1v - t24);
      }
    }
    // exchange: lk[row][unit u] at bufT + (row*32 + (u ^ (row&31)))*16
    #pragma unroll
    for (int j=0;j<4;j++){
      const int row = 16*(4*par+j)+l15;
      *(f32x4*)(bufT + (size_t)(row*32 + (((4*at+lg) ^ (row&31))&31))*16) = lkf[j];
    }
    lds_bar();
    #pragma unroll
    for (int jj=0;jj<4;jj++)
      lkR[jj] = *(const f32x4*)(bufT + (size_t)(kR*32 + (((4*p8+jj) ^ (kR&31))&31))*16);
    #pragma unroll
    for (int jj=0;jj<4;jj++){
      #pragma unroll
      for (int e=0;e<4;e++){
        const int row = 16*p8 + 4*jj + e;
        lkC[jj][e] = *(const float*)(bufT
            + (size_t)(row*32 + (((kR>>2) ^ (row&31))&31))*16 + (kR&3)*4);
      }
    }

    // ---- Sinkhorn: 10 iterations, base-2, lgkm-only barriers
    for (int it=0; it<10; it++){
      f32x4 y[4];
      #pragma unroll
      for (int jj=0;jj<4;jj++){
        y[jj] = lkR[jj];
        if (it) y[jj] += *(const f32x4*)&lvs[16*p8+4*jj];
      }
      f32x4 m4 = vmax4(vmax4(y[0],y[1]), vmax4(y[2],y[3]));
      float mx = fmaxf(fmaxf(m4[0],m4[1]), fmaxf(m4[2],m4[3]));
      mx = fmaxf(mx,__shfl_xor(mx,8)); mx = fmaxf(mx,__shfl_xor(mx,16));
      mx = fmaxf(mx,__shfl_xor(mx,32));
      f32x4 s4 = {0.f,0.f,0.f,0.f};
      #pragma unroll
      for (int jj=0;jj<4;jj++){
        #pragma unroll
        for (int e=0;e<4;e++) s4[e] += exp2f(y[jj][e]-mx);
      }
      float s = s4[0]+s4[1]+s4[2]+s4[3];
      s += __shfl_xor(s,8); s += __shfl_xor(s,16); s += __shfl_xor(s,32);
      luR = rho*(lmu2R - (mx + __log2f(s)));
      if (p8==0) lus[kR] = luR;
      lds_bar();
      #pragma unroll
      for (int jj=0;jj<4;jj++)
        y[jj] = lkC[jj] + *(const f32x4*)&lus[16*p8+4*jj];
      m4 = vmax4(vmax4(y[0],y[1]), vmax4(y[2],y[3]));
      mx = fmaxf(fmaxf(m4[0],m4[1]), fmaxf(m4[2],m4[3]));
      mx = fmaxf(mx,__shfl_xor(mx,8)); mx = fmaxf(mx,__shfl_xor(mx,16));
      mx = fmaxf(mx,__shfl_xor(mx,32));
      s4 = (f32x4){0.f,0.f,0.f,0.f};
      #pragma unroll
      for (int jj=0;jj<4;jj++){
        #pragma unroll
        for (int e=0;e<4;e++) s4[e] += exp2f(y[jj][e]-mx);
      }
      s = s4[0]+s4[1]+s4[2]+s4[3];
      s += __shfl_xor(s,8); s += __shfl_xor(s,16); s += __shfl_xor(s,32);
      lvC = rho*(lnu2C - (mx + __log2f(s)));
      if (p8==0) lvs[kR] = lvC;
      lds_bar();
    }

    if (outer==4){
      float cp = 0.f;
      float* Tb = T_out + (size_t)b*16384;
      #pragma unroll
      for (int jj=0;jj<4;jj++){
        const f32x4 lv4 = *(const f32x4*)&lvs[16*p8+4*jj];
        f32x4 t;
        #pragma unroll
        for (int e=0;e<4;e++) t[e] = exp2f(lkR[jj][e] + luR + lv4[e]);
        *(f32x4*)(Tb + kR*128 + 16*p8 + 4*jj) = t;
        const f32x4 pr = t*lkR[jj];
        cp += pr[0]+pr[1]+pr[2]+pr[3];
      }
      cp *= -eps*0.6931471805599453f;
      #pragma unroll
      for (int off=1;off<64;off<<=1) cp += __shfl_xor(cp, off);
      if (lane==0) redc[w] = cp;
      __syncthreads();
      if (tid==0){
        float tot = 0.f;
        #pragma unroll
        for (int w2=0;w2<16;w2++) tot += redc[w2];
        cost_out[b] = tot;
        sim_out[b]  = 1.0f/(1.0f + __expf(tot));
      }
    }
  }
}

// ---------------------------------------------------------------------------
extern "C" void kernel_launch(void* const* d_in, const int* in_sizes, int n_in,
                              void* d_out, int out_size, void* d_ws, size_t ws_size,
                              hipStream_t stream){
  const float* sq      = (const float*)d_in[0];
  const float* sr      = (const float*)d_in[1];
  const float* mask_q  = (const float*)d_in[2];
  const float* mask_r  = (const float*)d_in[3];
  const float* cq      = (const float*)d_in[4];
  const float* cr      = (const float*)d_in[5];
  const float* W1      = (const float*)d_in[6];
  const float* b1      = (const float*)d_in[7];
  const float* W2      = (const float*)d_in[8];
  const float* b2      = (const float*)d_in[9];
  const float* log_eps = (const float*)d_in[10];

  float* out  = (float*)d_out;
  float* sim  = out;                 // [256]
  float* Tm   = out + 256;           // [256][128][128]
  float* Cm   = Tm + 4194304;        // [256][128][128]
  float* cost = Cm + 4194304;        // [256]

  char* ws = (char*)d_ws;
  size_t off = 0;
  auto alloc = [&](size_t bytes)->void*{ void* p = ws + off; off += (bytes+255)&~(size_t)255; return p; };
  u16*   PQ  = (u16*)  alloc(67108864);   // P bf16 (65536x512); later loop planes
  u16*   HQ  = (u16*)  alloc(67108864);   // hidden H bf16 (65536x512)
  u16*   W1T = (u16*)  alloc(524288);
  u16*   W2T = (u16*)  alloc(524288);
  float* NP4 = (float*)alloc(1048576);    // per-cb row-norm partials [4][65536]
  float* LMU = (float*)alloc(131072);
  float* LNU = (float*)alloc(131072);
  float* MUA = (float*)alloc(131072);
  float* NUA = (float*)alloc(131072);
  (void)ws_size; (void)in_sizes; (void)n_in; (void)out_size;

  char* SQHL = (char*)PQ;                  // 16MB bf16 hi/lo Sq planes
  char* SRHL = (char*)PQ + 16777216;       // 16MB bf16 hi/lo Sr planes

  prologue_k<<<2176,256,0,stream>>>(W1, W2, W1T, W2T, mask_q, mask_r,
                                    LMU, LNU, MUA, NUA);
  gemm_k<1,0,1><<<2048,256,0,stream>>>(nullptr, sq, sr, W1T, b1, HQ, nullptr);
  gemm_k<0,1,0><<<2048,256,0,stream>>>(HQ, nullptr, nullptr, W2T, b2, PQ, NP4);
  pdist_all_k<<<768,256,0,stream>>>(PQ, NP4, cq, cr, Cm, SQHL, SRHL);
  fgw_loop_k<<<256,1024,0,stream>>>(SQHL, SRHL, Cm, MUA, NUA, LMU, LNU,
                                    log_eps, Tm, cost, sim);
}

// Round 12
// 403.959 us; speedup vs baseline: 1.0332x; 1.0332x over previous
//
#include <hip/hip_runtime.h>
#include <math.h>

typedef unsigned short u16;
typedef __attribute__((ext_vector_type(4))) float f32x4;
typedef __attribute__((ext_vector_type(8))) short bf16x8;
typedef __attribute__((ext_vector_type(4))) unsigned short u16x4;
typedef __attribute__((ext_vector_type(8))) unsigned short u16x8;

#define DEVI static __device__ __forceinline__

DEVI float b2f(u16 u){ union{float f; unsigned i;} v; v.i = ((unsigned)u)<<16; return v.f; }
DEVI u16 f2b(float f){ union{float f; unsigned i;} v; v.f=f;
  unsigned r = v.i + 0x7fffu + ((v.i>>16)&1u); return (u16)(r>>16); }
DEVI float u2f(unsigned u){ union{unsigned i; float f;} v; v.i=u; return v.f; }

// packed f32->2xbf16 (gfx950 native; no builtin -> inline asm, T12 recipe)
DEVI unsigned cvtpk(float a, float b){
  unsigned r;
  asm("v_cvt_pk_bf16_f32 %0, %1, %2" : "=v"(r) : "v"(a), "v"(b));
  return r;
}

// split f32x4 -> hi/lo bf16x4 via cvt_pk (~12 ops vs ~40 for software RNE)
DEVI void split4(const f32x4 x, u16x4* hi4, u16x4* lo4){
  unsigned h0 = cvtpk(x[0], x[1]);
  unsigned h1 = cvtpk(x[2], x[3]);
  unsigned l0 = cvtpk(x[0]-u2f(h0<<16), x[1]-u2f(h0&0xffff0000u));
  unsigned l1 = cvtpk(x[2]-u2f(h1<<16), x[3]-u2f(h1&0xffff0000u));
  union{unsigned u[2]; u16x4 v;} H,L;
  H.u[0]=h0; H.u[1]=h1; L.u[0]=l0; L.u[1]=l1;
  *hi4 = H.v; *lo4 = L.v;
}

DEVI void gload_lds16(const void* g, void* l){
  __builtin_amdgcn_global_load_lds((const __attribute__((address_space(1))) void*)g,
                                   (__attribute__((address_space(3))) void*)l, 16, 0, 0);
}

// LDS-only barrier: waits DS ops, does NOT drain vmcnt (keeps prefetch in flight)
DEVI void lds_bar(){ asm volatile("s_waitcnt lgkmcnt(0)\n\ts_barrier" ::: "memory"); }

DEVI f32x4 vmax4(f32x4 a, f32x4 b){
  f32x4 r; r[0]=fmaxf(a[0],b[0]); r[1]=fmaxf(a[1],b[1]);
  r[2]=fmaxf(a[2],b[2]); r[3]=fmaxf(a[3],b[3]); return r;
}

// ---------------------------------------------------------------------------
// Merged prologue: blocks [0,2048): W1/W2 -> bf16 [c][k]; blocks [2048,2176):
// mu/nu + base-2 logs (2 batches per 256-thread block).
__global__ void prologue_k(const float* __restrict__ W1, const float* __restrict__ W2,
                           u16* __restrict__ W1T, u16* __restrict__ W2T,
                           const float* __restrict__ mask_q, const float* __restrict__ mask_r,
                           float* __restrict__ lmu2, float* __restrict__ lnu2,
                           float* __restrict__ mu, float* __restrict__ nu){
  const int blk = blockIdx.x;
  if (blk < 2048){
    const float* W = (blk<1024)? W1 : W2;
    u16* Wt = (blk<1024)? W1T : W2T;
    int id = (blk&1023)*256 + threadIdx.x;
    int k = id>>9, c = id&511;
    Wt[c*512 + k] = f2b(W[id]);
  } else {
    __shared__ float red[2][4];
    const int h = threadIdx.x>>7, t = threadIdx.x&127;
    const int b = (blk-2048)*2 + h;
    float mq = mask_q[b*128+t], mr = mask_r[b*128+t];
    float s1 = mq, s2 = mr;
    #pragma unroll
    for (int off=1;off<64;off<<=1){ s1 += __shfl_xor(s1,off); s2 += __shfl_xor(s2,off); }
    if ((t&63)==0){ red[h][(t>>6)&1] = s1; red[h][2+((t>>6)&1)] = s2; }
    __syncthreads();
    float sumq = red[h][0]+red[h][1], sumr = red[h][2]+red[h][3];
    float muv = mq/(sumq+1e-8f), nuv = mr/(sumr+1e-8f);
    lmu2[b*128+t] = __log2f(fmaxf(muv,1e-8f));
    lnu2[b*128+t] = __log2f(fmaxf(nuv,1e-8f));
    mu[b*128+t] = muv;
    nu[b*128+t] = nuv;
  }
}

// ---------------------------------------------------------------------------
// OUT[r][c] = act(sum_k X[r][k]*W[k][c] + bias[c]); Wt bf16 [c][k].
// AF32: A-tile reg-staged from f32 via cvt_pk. NORM: per-cb partials to NP4.
// Epilogue via LDS transpose with cvt_pk pairs.
template<int ACT, int NORM, int AF32>
__global__ __launch_bounds__(256) void gemm_k(const u16* __restrict__ X,
    const float* __restrict__ Xf1, const float* __restrict__ Xf2,
    const u16* __restrict__ Wt, const float* __restrict__ bias, u16* __restrict__ OUT,
    float* __restrict__ NP4){
  __shared__ __align__(16) u16 smem[17920];
  u16* sA = smem;
  u16* sB = smem + 8192;
  const int tid = threadIdx.x, wave = tid>>6, lane = tid&63;
  const int bid = (blockIdx.x&7)*256 + (blockIdx.x>>3);
  const int rblk = bid>>2, cb = (bid&3)<<7;
  const u16* Xb = AF32 ? nullptr : (X + (size_t)rblk*(128*512));
  const float* Xbf = AF32 ? (rblk<256 ? Xf1 + (size_t)rblk*65536
                                      : Xf2 + (size_t)(rblk-256)*65536) : nullptr;
  const u16* Wb = Wt + (size_t)cb*512;
  const int lrow = lane&15, lg = lane>>4, wr = wave>>1, wc = wave&1;
  f32x4 acc[4][4] = {};
  for (int s=0;s<8;s++){
    const int k0 = s<<6;
    #pragma unroll
    for (int q=0;q<4;q++){
      const int i = (wave<<2)+q;
      const int row = (i<<3) + (lane>>3);
      const int cd = (lane&7) ^ (row&7);
      if (AF32){
        const float* src = Xbf + row*512 + k0 + (cd<<3);
        const f32x4 va = *(const f32x4*)src;
        const f32x4 vb = *(const f32x4*)(src+4);
        union{unsigned u[4]; u16x8 v;} U;
        U.u[0]=cvtpk(va[0],va[1]); U.u[1]=cvtpk(va[2],va[3]);
        U.u[2]=cvtpk(vb[0],vb[1]); U.u[3]=cvtpk(vb[2],vb[3]);
        *(u16x8*)((char*)sA + i*1024 + lane*16) = U.v;
      } else {
        gload_lds16(Xb + row*512 + k0 + (cd<<3), sA + i*512);
      }
      gload_lds16(Wb + row*512 + k0 + (cd<<3), sB + i*512);
    }
    __syncthreads();
    #pragma unroll
    for (int kh=0;kh<2;kh++){
      bf16x8 a_[4], b_[4];
      #pragma unroll
      for (int i=0;i<4;i++){
        const int ra = (wr<<6)+(i<<4)+lrow;
        a_[i] = *(const bf16x8*)(sA + ra*64 + ((((kh<<2)+lg)^(ra&7))<<3));
        const int rb = (wc<<6)+(i<<4)+lrow;
        b_[i] = *(const bf16x8*)(sB + rb*64 + ((((kh<<2)+lg)^(rb&7))<<3));
      }
      #pragma unroll
      for (int i=0;i<4;i++)
        #pragma unroll
        for (int j=0;j<4;j++)
          acc[i][j] = __builtin_amdgcn_mfma_f32_16x16x32_bf16(a_[i], b_[j], acc[i][j], 0,0,0);
    }
    __syncthreads();
  }
  #pragma unroll
  for (int j=0;j<4;j++){
    const int colb = (wc<<6) + (j<<4) + lrow;
    const float bv = bias[cb + colb];
    #pragma unroll
    for (int i=0;i<4;i++){
      const int rowb = (wr<<6)+(i<<4)+(lg<<2);
      float v0 = acc[i][j][0]+bv, v1 = acc[i][j][1]+bv;
      float v2 = acc[i][j][2]+bv, v3 = acc[i][j][3]+bv;
      if (ACT){ v0=fmaxf(v0,0.f); v1=fmaxf(v1,0.f); v2=fmaxf(v2,0.f); v3=fmaxf(v3,0.f); }
      unsigned pA = cvtpk(v0,v1), pB = cvtpk(v2,v3);
      smem[(rowb  )*140 + colb] = (u16)pA;
      smem[(rowb+1)*140 + colb] = (u16)(pA>>16);
      smem[(rowb+2)*140 + colb] = (u16)pB;
      smem[(rowb+3)*140 + colb] = (u16)(pB>>16);
    }
  }
  __syncthreads();
  const int chunk = lane&15, rql = lane>>4;
  float ns[8];
  #pragma unroll
  for (int it=0; it<8; it++){
    const int rowb = it*16 + wave*4 + rql;
    u16x8 v8 = *(const u16x8*)(smem + rowb*140 + chunk*8);
    *(u16x8*)(OUT + (size_t)((rblk<<7)+rowb)*512 + cb + chunk*8) = v8;
    if (NORM){
      float s = 0.f;
      #pragma unroll
      for (int e=0;e<8;e++){ float f = b2f(v8[e]); s = fmaf(f,f,s); }
      s += __shfl_xor(s,1); s += __shfl_xor(s,2);
      s += __shfl_xor(s,4); s += __shfl_xor(s,8);
      ns[it] = s;
    }
  }
  if (NORM && chunk==0){
    #pragma unroll
    for (int it=0;it<8;it++)
      NP4[(size_t)(bid&3)*65536 + (rblk<<7) + it*16 + wave*4 + rql] = ns[it];
  }
}

// ---------------------------------------------------------------------------
// pdist_all: 768 blocks. [0,256): C from P; [256,512): Sq planes; [512,768): Sr.
__global__ __launch_bounds__(256) void pdist_all_k(const u16* __restrict__ PQ,
    const float* __restrict__ NP4, const float* __restrict__ cq,
    const float* __restrict__ cr, float* __restrict__ Cm,
    char* __restrict__ SQHL, char* __restrict__ SRHL){
  __shared__ __align__(16) u16 sA[8192];
  __shared__ __align__(16) u16 sB[8192];
  __shared__ float nA[128], nB[128];
  const int tid = threadIdx.x, wave = tid>>6, lane = tid&63;
  const int lrow = lane&15, lg = lane>>4, wr = wave>>1, wc = wave&1;
  const int b = blockIdx.x & 255;

  if (blockIdx.x < 256){
    if (tid < 128){
      const int row = b*128 + tid;
      nA[tid] = NP4[row] + NP4[65536+row] + NP4[131072+row] + NP4[196608+row];
    } else {
      const int row = 32768 + b*128 + (tid-128);
      nB[tid-128] = NP4[row] + NP4[65536+row] + NP4[131072+row] + NP4[196608+row];
    }
    const u16* Ab = PQ + (size_t)b*(128*512);
    const u16* Bb = PQ + (size_t)(32768 + b*128)*512;
    f32x4 acc[4][4] = {};
    for (int s=0;s<8;s++){
      const int k0 = s<<6;
      #pragma unroll
      for (int q=0;q<4;q++){
        const int i = (wave<<2)+q;
        const int row = (i<<3) + (lane>>3);
        const int cd = (lane&7) ^ (row&7);
        gload_lds16(Ab + row*512 + k0 + (cd<<3), sA + i*512);
        gload_lds16(Bb + row*512 + k0 + (cd<<3), sB + i*512);
      }
      __syncthreads();
      #pragma unroll
      for (int kh=0;kh<2;kh++){
        bf16x8 a_[4], b_[4];
        #pragma unroll
        for (int i=0;i<4;i++){
          const int ra = (wr<<6)+(i<<4)+lrow;
          a_[i] = *(const bf16x8*)(sA + ra*64 + ((((kh<<2)+lg)^(ra&7))<<3));
          const int rb = (wc<<6)+(i<<4)+lrow;
          b_[i] = *(const bf16x8*)(sB + rb*64 + ((((kh<<2)+lg)^(rb&7))<<3));
        }
        #pragma unroll
        for (int i=0;i<4;i++)
          #pragma unroll
          for (int j=0;j<4;j++)
            acc[i][j] = __builtin_amdgcn_mfma_f32_16x16x32_bf16(a_[i], b_[j], acc[i][j], 0,0,0);
      }
      __syncthreads();
    }
    #pragma unroll
    for (int j=0;j<4;j++){
      const int col = (wc<<6)+(j<<4)+lrow;
      const float nbv = nB[col];
      #pragma unroll
      for (int i=0;i<4;i++){
        const int row0 = (wr<<6)+(i<<4)+(lg<<2);
        #pragma unroll
        for (int r=0;r<4;r++){
          float n2 = nA[row0+r] + nbv - 2.0f*acc[i][j][r];
          Cm[(size_t)b*16384 + (size_t)(row0+r)*128 + col] = sqrtf(fmaxf(n2, 1e-6f));
        }
      }
    }
  } else {
    const float* Sb = ((blockIdx.x < 512)? cq : cr) + (size_t)b*65536;
    char* SHL = (blockIdx.x < 512)? SQHL : SRHL;
    f32x4 acc[4][4] = {};
    float nacc[4] = {0.f,0.f,0.f,0.f};
    for (int s=0;s<8;s++){
      const int k0 = s<<6;
      #pragma unroll
      for (int q=0;q<4;q++){
        const int i = (wave<<2)+q;
        const int row = (i<<3) + (lane>>3);
        const int cd = (lane&7) ^ (row&7);
        const float* src = Sb + row*512 + k0 + (cd<<3);
        const f32x4 va = *(const f32x4*)src;
        const f32x4 vb = *(const f32x4*)(src+4);
        union{unsigned u[4]; u16x8 v;} U;
        U.u[0]=cvtpk(va[0],va[1]); U.u[1]=cvtpk(va[2],va[3]);
        U.u[2]=cvtpk(vb[0],vb[1]); U.u[3]=cvtpk(vb[2],vb[3]);
        #pragma unroll
        for (int p2=0;p2<4;p2++){
          float f0 = u2f(U.u[p2]<<16), f1 = u2f(U.u[p2]&0xffff0000u);
          nacc[q] = fmaf(f0,f0,nacc[q]);
          nacc[q] = fmaf(f1,f1,nacc[q]);
        }
        *(u16x8*)((char*)sA + i*1024 + lane*16) = U.v;
      }
      __syncthreads();
      #pragma unroll
      for (int kh=0;kh<2;kh++){
        bf16x8 a_[4], b_[4];
        #pragma unroll
        for (int i=0;i<4;i++){
          const int ra = (wr<<6)+(i<<4)+lrow;
          a_[i] = *(const bf16x8*)(sA + ra*64 + ((((kh<<2)+lg)^(ra&7))<<3));
          const int rb = (wc<<6)+(i<<4)+lrow;
          b_[i] = *(const bf16x8*)(sA + rb*64 + ((((kh<<2)+lg)^(rb&7))<<3));
        }
        #pragma unroll
        for (int i=0;i<4;i++)
          #pragma unroll
          for (int j=0;j<4;j++)
            acc[i][j] = __builtin_amdgcn_mfma_f32_16x16x32_bf16(a_[i], b_[j], acc[i][j], 0,0,0);
      }
      __syncthreads();
    }
    #pragma unroll
    for (int q=0;q<4;q++){
      float v = nacc[q];
      v += __shfl_xor(v,1); v += __shfl_xor(v,2); v += __shfl_xor(v,4);
      if ((lane&7)==0) nA[((wave<<2)+q)*8 + (lane>>3)] = v;
    }
    __syncthreads();
    #pragma unroll
    for (int j=0;j<4;j++){
      const int col = (wc<<6)+(j<<4)+lrow;
      const float nbv = nA[col];
      #pragma unroll
      for (int i=0;i<4;i++){
        const int row0 = (wr<<6)+(i<<4)+(lg<<2);
        f32x4 sv;
        #pragma unroll
        for (int r=0;r<4;r++){
          float n2 = nA[row0+r] + nbv - 2.0f*acc[i][j][r];
          sv[r] = sqrtf(fmaxf(n2, 1e-6f));
        }
        u16x4 hi4, lo4;
        split4(sv, &hi4, &lo4);
        const int sa = col*256 + ((((row0>>3)^col)&15)<<4) + ((row0&7)<<1);
        char* base = SHL + (size_t)b*65536;
        *(u16x4*)(base + sa) = hi4;
        *(u16x4*)(base + 32768 + sa) = lo4;
      }
    }
  }
}

// ---------------------------------------------------------------------------
// 5-iter FGW loop, 512 threads/block, base-2 log-domain Sinkhorn.
// lk exchange via linear XOR-slotted buffer; Sr prefetched during Sinkhorn;
// Sinkhorn barriers lgkm-only; plane splits via cvt_pk.
__global__ __launch_bounds__(512,1) void fgw_loop_k(
    const char* __restrict__ SQHL, const char* __restrict__ SRHL,
    const float* __restrict__ C_g,
    const float* __restrict__ MU, const float* __restrict__ NU,
    const float* __restrict__ LMU2, const float* __restrict__ LNU2,
    const float* __restrict__ log_eps,
    float* __restrict__ T_out, float* __restrict__ cost_out, float* __restrict__ sim_out)
{
  __shared__ __align__(16) char bufT[65536];
  __shared__ __align__(16) char bufS[65536];
  __shared__ __align__(16) float avs[128], bvs[128], t1s[128], t2s[128];
  __shared__ __align__(16) float lus[128], lvs[128];
  __shared__ float redc[8];

  const int b = blockIdx.x, tid = threadIdx.x;
  const int w = tid>>6, lane = tid&63, l15 = lane&15, lg = lane>>4;
  const char* SqHLb = SQHL + (size_t)b*65536;
  const char* SrHLb = SRHL + (size_t)b*65536;
  const float* Cb   = C_g + (size_t)b*16384;
  const float* MUb  = MU + b*128;
  const float* NUb  = NU + b*128;

  float eps = __expf(log_eps[0]); eps = fminf(fmaxf(eps,0.01f),0.5f);
  const float rho = 0.1f/(0.1f+eps);
  const float hscale = 0.5f*1.4426950408889634f/eps;

  const int kR = 16*w + l15;
  const int n0 = 16*w + 4*lg;
  const float lmu2R = LMU2[b*128+kR];
  const float lnu2C = LNU2[b*128+kR];

  const int rowA256 = (16*w + l15)*256;
  const int glo2 = lg ^ (l15 & 3);
  const int ghi2 = l15 & 12;
  const int wtail = l15*256 + ((((2*w + (lg>>1)) ^ l15)&15)<<4) + ((lg&1)<<3);
  const int slotW = lg*16 + (l15^lg);

  f32x4 Cf2[8];
  #pragma unroll
  for (int kt=0;kt<8;kt++)
    Cf2[kt] = -hscale * (*(const f32x4*)(Cb + (size_t)(16*kt+l15)*128 + n0));

  f32x4 lkR[8], lkC[8];
  float luR = 0.f, lvC = 0.f;

  #pragma unroll
  for (int r2=0;r2<8;r2++)
    gload_lds16(SrHLb + r2*8192 + tid*16, bufS + r2*8192 + tid*16);

  for (int outer=0; outer<5; outer++){
    // ---- P0: T planes + avs; bvs via closed form
    {
      f32x4 avp = {0.f,0.f,0.f,0.f};
      #pragma unroll
      for (int q=0;q<8;q++){
        f32x4 TR;
        if (outer==0){
          const f32x4 nu4 = *(const f32x4*)(NUb + 16*q + 4*lg);
          TR = MUb[kR]*nu4;
        } else {
          const f32x4 lv4 = *(const f32x4*)&lvs[16*q + 4*lg];
          #pragma unroll
          for (int e=0;e<4;e++) TR[e] = exp2f(lkR[q][e] + luR + lv4[e]);
        }
        u16x4 hi4, lo4;
        split4(TR, &hi4, &lo4);
        const int sa = kR*256 + ((((2*q+(lg>>1)) ^ l15)&15)<<4) + ((lg&1)<<3);
        *(u16x4*)(bufT + sa) = hi4;
        *(u16x4*)(bufT + 32768 + sa) = lo4;
        avp += TR;
      }
      float av = avp[0]+avp[1]+avp[2]+avp[3];
      av += __shfl_xor(av,16); av += __shfl_xor(av,32);
      if (lg==0){
        avs[kR] = av;
        bvs[kR] = (outer==0) ? NUb[kR] : exp2f(lnu2C - 10.f*eps*lvC);
      }
    }
    __syncthreads();

    // ---- P1: t2 from Sr planes + bvs; phase A MFMA
    {
      const int p = tid>>2, sub = tid&3;
      float s2 = 0.f;
      #pragma unroll
      for (int gg=0; gg<4; gg++){
        const int g = 4*sub+gg;
        const int off = p*256 + (((g ^ (p&15))&15)<<4);
        const u16x8 h8 = *(const u16x8*)(bufS + off);
        const u16x8 l8 = *(const u16x8*)(bufS + 32768 + off);
        const f32x4 bva = *(const f32x4*)&bvs[8*g];
        const f32x4 bvb = *(const f32x4*)&bvs[8*g+4];
        #pragma unroll
        for (int e=0;e<4;e++){
          float x = b2f(h8[e]) + b2f(l8[e]);
          s2 = fmaf(bva[e], x*x, s2);
          float y2 = b2f(h8[4+e]) + b2f(l8[4+e]);
          s2 = fmaf(bvb[e], y2*y2, s2);
        }
      }
      s2 += __shfl_xor(s2,1); s2 += __shfl_xor(s2,2);
      if (sub==0) t2s[p] = s2;
    }
    f32x4 acc1[8] = {};
    #pragma unroll
    for (int qt=0;qt<4;qt++){
      const int colOff = (((4*qt) ^ ghi2) | glo2) << 4;
      const bf16x8 ahi = *(const bf16x8*)(bufT + rowA256 + colOff);
      const bf16x8 alo = *(const bf16x8*)(bufT + 32768 + rowA256 + colOff);
      const int bbase = l15*256 + colOff;
      #pragma unroll
      for (int nt=0;nt<8;nt++){
        const bf16x8 bhi = *(const bf16x8*)(bufS + nt*4096 + bbase);
        const bf16x8 blo = *(const bf16x8*)(bufS + 32768 + nt*4096 + bbase);
        acc1[nt] = __builtin_amdgcn_mfma_f32_16x16x32_bf16(ahi, bhi, acc1[nt], 0,0,0);
        acc1[nt] = __builtin_amdgcn_mfma_f32_16x16x32_bf16(ahi, blo, acc1[nt], 0,0,0);
        acc1[nt] = __builtin_amdgcn_mfma_f32_16x16x32_bf16(alo, bhi, acc1[nt], 0,0,0);
      }
    }
    __syncthreads();

    // ---- P2: stage Sq; write TSr^T planes (cvt_pk split)
    #pragma unroll
    for (int r2=0;r2<8;r2++)
      gload_lds16(SqHLb + r2*8192 + tid*16, bufS + r2*8192 + tid*16);
    #pragma unroll
    for (int nt=0;nt<8;nt++){
      u16x4 hi4, lo4;
      split4(acc1[nt], &hi4, &lo4);
      const int sa = nt*4096 + wtail;
      *(u16x4*)(bufT + sa) = hi4;
      *(u16x4*)(bufT + 32768 + sa) = lo4;
    }
    __syncthreads();

    // ---- P3: t1 from Sq planes + avs; phase B MFMA
    {
      const int p = tid>>2, sub = tid&3;
      float s1 = 0.f;
      #pragma unroll
      for (int gg=0; gg<4; gg++){
        const int g = 4*sub+gg;
        const int off = p*256 + (((g ^ (p&15))&15)<<4);
        const u16x8 h8 = *(const u16x8*)(bufS + off);
        const u16x8 l8 = *(const u16x8*)(bufS + 32768 + off);
        const f32x4 ava = *(const f32x4*)&avs[8*g];
        const f32x4 avb = *(const f32x4*)&avs[8*g+4];
        #pragma unroll
        for (int e=0;e<4;e++){
          float x = b2f(h8[e]) + b2f(l8[e]);
          s1 = fmaf(ava[e], x*x, s1);
          float y2 = b2f(h8[4+e]) + b2f(l8[4+e]);
          s1 = fmaf(avb[e], y2*y2, s1);
        }
      }
      s1 += __shfl_xor(s1,1); s1 += __shfl_xor(s1,2);
      if (sub==0) t1s[p] = s1;
    }
    f32x4 acc2[8] = {};
    #pragma unroll
    for (int qt=0;qt<4;qt++){
      const int colOff = (((4*qt) ^ ghi2) | glo2) << 4;
      const bf16x8 ahi = *(const bf16x8*)(bufT + rowA256 + colOff);
      const bf16x8 alo = *(const bf16x8*)(bufT + 32768 + rowA256 + colOff);
      const int bbase = l15*256 + colOff;
      #pragma unroll
      for (int kt=0;kt<8;kt++){
        const bf16x8 bhi = *(const bf16x8*)(bufS + kt*4096 + bbase);
        const bf16x8 blo = *(const bf16x8*)(bufS + 32768 + kt*4096 + bbase);
        acc2[kt] = __builtin_amdgcn_mfma_f32_16x16x32_bf16(ahi, bhi, acc2[kt], 0,0,0);
        acc2[kt] = __builtin_amdgcn_mfma_f32_16x16x32_bf16(ahi, blo, acc2[kt], 0,0,0);
        acc2[kt] = __builtin_amdgcn_mfma_f32_16x16x32_bf16(alo, bhi, acc2[kt], 0,0,0);
      }
    }
    __syncthreads();

    // ---- P4: prefetch next Sr; lk build + exchange
    if (outer<4){
      #pragma unroll
      for (int r2=0;r2<8;r2++)
        gload_lds16(SrHLb + r2*8192 + tid*16, bufS + r2*8192 + tid*16);
    }
    f32x4 lkf[8];
    {
      const f32x4 t24 = *(const f32x4*)&t2s[n0];
      #pragma unroll
      for (int kt=0;kt<8;kt++){
        const float t1v = t1s[16*kt+l15];
        lkf[kt] = Cf2[kt] + hscale*(2.0f*acc2[kt] - t1v - t24);
      }
    }
    #pragma unroll
    for (int kt=0;kt<8;kt++)
      *(f32x4*)(bufT + (((kt*8+w)*64 + slotW)<<4)) = lkf[kt];
    lds_bar();
    #pragma unroll
    for (int q=0;q<8;q++)
      lkR[q] = *(const f32x4*)(bufT + (((w*8+q)*64 + slotW)<<4));
    #pragma unroll
    for (int q=0;q<8;q++){
      #pragma unroll
      for (int e=0;e<4;e++){
        const int slotC = (l15>>2)*16 + ((4*lg+e) ^ (l15>>2));
        lkC[q][e] = *(const float*)(bufT + (((q*8+w)*64 + slotC)<<4) + ((l15&3)<<2));
      }
    }

    // ---- Sinkhorn: 10 iterations, base-2, lgkm-only barriers
    for (int it=0; it<10; it++){
      f32x4 y[8];
      #pragma unroll
      for (int q=0;q<8;q++){
        y[q] = lkR[q];
        if (it) y[q] += *(const f32x4*)&lvs[16*q+4*lg];
      }
      f32x4 m4 = vmax4(vmax4(vmax4(y[0],y[1]),vmax4(y[2],y[3])),
                       vmax4(vmax4(y[4],y[5]),vmax4(y[6],y[7])));
      float mx = fmaxf(fmaxf(m4[0],m4[1]), fmaxf(m4[2],m4[3]));
      mx = fmaxf(mx,__shfl_xor(mx,16)); mx = fmaxf(mx,__shfl_xor(mx,32));
      f32x4 s4 = {0.f,0.f,0.f,0.f};
      #pragma unroll
      for (int q=0;q<8;q++){
        #pragma unroll
        for (int e=0;e<4;e++) s4[e] += exp2f(y[q][e]-mx);
      }
      float s = s4[0]+s4[1]+s4[2]+s4[3];
      s += __shfl_xor(s,16); s += __shfl_xor(s,32);
      luR = rho*(lmu2R - (mx + __log2f(s)));
      if (lg==0) lus[kR] = luR;
      lds_bar();
      #pragma unroll
      for (int q=0;q<8;q++)
        y[q] = lkC[q] + *(const f32x4*)&lus[16*q+4*lg];
      m4 = vmax4(vmax4(vmax4(y[0],y[1]),vmax4(y[2],y[3])),
                 vmax4(vmax4(y[4],y[5]),vmax4(y[6],y[7])));
      mx = fmaxf(fmaxf(m4[0],m4[1]), fmaxf(m4[2],m4[3]));
      mx = fmaxf(mx,__shfl_xor(mx,16)); mx = fmaxf(mx,__shfl_xor(mx,32));
      s4 = (f32x4){0.f,0.f,0.f,0.f};
      #pragma unroll
      for (int q=0;q<8;q++){
        #pragma unroll
        for (int e=0;e<4;e++) s4[e] += exp2f(y[q][e]-mx);
      }
      s = s4[0]+s4[1]+s4[2]+s4[3];
      s += __shfl_xor(s,16); s += __shfl_xor(s,32);
      lvC = rho*(lnu2C - (mx + __log2f(s)));
      if (lg==0) lvs[kR] = lvC;
      lds_bar();
    }

    if (outer==4){
      float cp = 0.f;
      float* Tb = T_out + (size_t)b*16384;
      #pragma unroll
      for (int q=0;q<8;q++){
        const f32x4 lv4 = *(const f32x4*)&lvs[16*q+4*lg];
        f32x4 t;
        #pragma unroll
        for (int e=0;e<4;e++) t[e] = exp2f(lkR[q][e] + luR + lv4[e]);
        *(f32x4*)(Tb + kR*128 + 16*q + 4*lg) = t;
        const f32x4 pr = t*lkR[q];
        cp += pr[0]+pr[1]+pr[2]+pr[3];
      }
      cp *= -eps*0.6931471805599453f;
      #pragma unroll
      for (int off=1;off<64;off<<=1) cp += __shfl_xor(cp, off);
      if (lane==0) redc[w] = cp;
      __syncthreads();
      if (tid==0){
        float tot = 0.f;
        #pragma unroll
        for (int w2=0;w2<8;w2++) tot += redc[w2];
        cost_out[b] = tot;
        sim_out[b]  = 1.0f/(1.0f + __expf(tot));
      }
    }
  }
}

// ---------------------------------------------------------------------------
extern "C" void kernel_launch(void* const* d_in, const int* in_sizes, int n_in,
                              void* d_out, int out_size, void* d_ws, size_t ws_size,
                              hipStream_t stream){
  const float* sq      = (const float*)d_in[0];
  const float* sr      = (const float*)d_in[1];
  const float* mask_q  = (const float*)d_in[2];
  const float* mask_r  = (const float*)d_in[3];
  const float* cq      = (const float*)d_in[4];
  const float* cr      = (const float*)d_in[5];
  const float* W1      = (const float*)d_in[6];
  const float* b1      = (const float*)d_in[7];
  const float* W2      = (const float*)d_in[8];
  const float* b2      = (const float*)d_in[9];
  const float* log_eps = (const float*)d_in[10];

  float* out  = (float*)d_out;
  float* sim  = out;                 // [256]
  float* Tm   = out + 256;           // [256][128][128]
  float* Cm   = Tm + 4194304;        // [256][128][128]
  float* cost = Cm + 4194304;        // [256]

  char* ws = (char*)d_ws;
  size_t off = 0;
  auto alloc = [&](size_t bytes)->void*{ void* p = ws + off; off += (bytes+255)&~(size_t)255; return p; };
  u16*   PQ  = (u16*)  alloc(67108864);   // P bf16 (65536x512); later loop planes
  u16*   HQ  = (u16*)  alloc(67108864);   // hidden H bf16 (65536x512)
  u16*   W1T = (u16*)  alloc(524288);
  u16*   W2T = (u16*)  alloc(524288);
  float* NP4 = (float*)alloc(1048576);    // per-cb row-norm partials [4][65536]
  float* LMU = (float*)alloc(131072);
  float* LNU = (float*)alloc(131072);
  float* MUA = (float*)alloc(131072);
  float* NUA = (float*)alloc(131072);
  (void)ws_size; (void)in_sizes; (void)n_in; (void)out_size;

  char* SQHL = (char*)PQ;                  // 16MB bf16 hi/lo Sq planes
  char* SRHL = (char*)PQ + 16777216;       // 16MB bf16 hi/lo Sr planes

  prologue_k<<<2176,256,0,stream>>>(W1, W2, W1T, W2T, mask_q, mask_r,
                                    LMU, LNU, MUA, NUA);
  gemm_k<1,0,1><<<2048,256,0,stream>>>(nullptr, sq, sr, W1T, b1, HQ, nullptr);
  gemm_k<0,1,0><<<2048,256,0,stream>>>(HQ, nullptr, nullptr, W2T, b2, PQ, NP4);
  pdist_all_k<<<768,256,0,stream>>>(PQ, NP4, cq, cr, Cm, SQHL, SRHL);
  fgw_loop_k<<<256,512,0,stream>>>(SQHL, SRHL, Cm, MUA, NUA, LMU, LNU,
                                   log_eps, Tm, cost, sim);
}

// Round 13
// 399.178 us; speedup vs baseline: 1.0456x; 1.0120x over previous
//
#include <hip/hip_runtime.h>
#include <math.h>

typedef unsigned short u16;
typedef __attribute__((ext_vector_type(4))) float f32x4;
typedef __attribute__((ext_vector_type(8))) short bf16x8;
typedef __attribute__((ext_vector_type(4))) unsigned short u16x4;
typedef __attribute__((ext_vector_type(8))) unsigned short u16x8;

#define DEVI static __device__ __forceinline__

DEVI float b2f(u16 u){ union{float f; unsigned i;} v; v.i = ((unsigned)u)<<16; return v.f; }
DEVI u16 f2b(float f){ union{float f; unsigned i;} v; v.f=f;
  unsigned r = v.i + 0x7fffu + ((v.i>>16)&1u); return (u16)(r>>16); }
DEVI float u2f(unsigned u){ union{unsigned i; float f;} v; v.i=u; return v.f; }

// packed f32->2xbf16 (gfx950 native; no builtin -> inline asm, T12 recipe)
DEVI unsigned cvtpk(float a, float b){
  unsigned r;
  asm("v_cvt_pk_bf16_f32 %0, %1, %2" : "=v"(r) : "v"(a), "v"(b));
  return r;
}

// split f32x4 -> hi/lo bf16x4 via cvt_pk
DEVI void split4(const f32x4 x, u16x4* hi4, u16x4* lo4){
  unsigned h0 = cvtpk(x[0], x[1]);
  unsigned h1 = cvtpk(x[2], x[3]);
  unsigned l0 = cvtpk(x[0]-u2f(h0<<16), x[1]-u2f(h0&0xffff0000u));
  unsigned l1 = cvtpk(x[2]-u2f(h1<<16), x[3]-u2f(h1&0xffff0000u));
  union{unsigned u[2]; u16x4 v;} H,L;
  H.u[0]=h0; H.u[1]=h1; L.u[0]=l0; L.u[1]=l1;
  *hi4 = H.v; *lo4 = L.v;
}

DEVI void gload_lds16(const void* g, void* l){
  __builtin_amdgcn_global_load_lds((const __attribute__((address_space(1))) void*)g,
                                   (__attribute__((address_space(3))) void*)l, 16, 0, 0);
}

// LDS-only barrier: waits DS ops, does NOT drain vmcnt (keeps prefetch in flight)
DEVI void lds_bar(){ asm volatile("s_waitcnt lgkmcnt(0)\n\ts_barrier" ::: "memory"); }

DEVI f32x4 vmax4(f32x4 a, f32x4 b){
  f32x4 r; r[0]=fmaxf(a[0],b[0]); r[1]=fmaxf(a[1],b[1]);
  r[2]=fmaxf(a[2],b[2]); r[3]=fmaxf(a[3],b[3]); return r;
}

// ---------------------------------------------------------------------------
// Merged prologue: blocks [0,2048): W1/W2 -> bf16 [c][k]; blocks [2048,2176):
// mu/nu + base-2 logs (2 batches per 256-thread block).
__global__ void prologue_k(const float* __restrict__ W1, const float* __restrict__ W2,
                           u16* __restrict__ W1T, u16* __restrict__ W2T,
                           const float* __restrict__ mask_q, const float* __restrict__ mask_r,
                           float* __restrict__ lmu2, float* __restrict__ lnu2,
                           float* __restrict__ mu, float* __restrict__ nu){
  const int blk = blockIdx.x;
  if (blk < 2048){
    const float* W = (blk<1024)? W1 : W2;
    u16* Wt = (blk<1024)? W1T : W2T;
    int id = (blk&1023)*256 + threadIdx.x;
    int k = id>>9, c = id&511;
    Wt[c*512 + k] = f2b(W[id]);
  } else {
    __shared__ float red[2][4];
    const int h = threadIdx.x>>7, t = threadIdx.x&127;
    const int b = (blk-2048)*2 + h;
    float mq = mask_q[b*128+t], mr = mask_r[b*128+t];
    float s1 = mq, s2 = mr;
    #pragma unroll
    for (int off=1;off<64;off<<=1){ s1 += __shfl_xor(s1,off); s2 += __shfl_xor(s2,off); }
    if ((t&63)==0){ red[h][(t>>6)&1] = s1; red[h][2+((t>>6)&1)] = s2; }
    __syncthreads();
    float sumq = red[h][0]+red[h][1], sumr = red[h][2]+red[h][3];
    float muv = mq/(sumq+1e-8f), nuv = mr/(sumr+1e-8f);
    lmu2[b*128+t] = __log2f(fmaxf(muv,1e-8f));
    lnu2[b*128+t] = __log2f(fmaxf(nuv,1e-8f));
    mu[b*128+t] = muv;
    nu[b*128+t] = nuv;
  }
}

// ---------------------------------------------------------------------------
// OUT[r][c] = act(sum_k X[r][k]*W[k][c] + bias[c]); Wt bf16 [c][k].
// AF32: A-tile reg-staged from f32 via cvt_pk. NORM: per-cb partials to NP4.
// Epilogue via LDS transpose with cvt_pk pairs.
template<int ACT, int NORM, int AF32>
__global__ __launch_bounds__(256) void gemm_k(const u16* __restrict__ X,
    const float* __restrict__ Xf1, const float* __restrict__ Xf2,
    const u16* __restrict__ Wt, const float* __restrict__ bias, u16* __restrict__ OUT,
    float* __restrict__ NP4){
  __shared__ __align__(16) u16 smem[17920];
  u16* sA = smem;
  u16* sB = smem + 8192;
  const int tid = threadIdx.x, wave = tid>>6, lane = tid&63;
  const int bid = (blockIdx.x&7)*256 + (blockIdx.x>>3);
  const int rblk = bid>>2, cb = (bid&3)<<7;
  const u16* Xb = AF32 ? nullptr : (X + (size_t)rblk*(128*512));
  const float* Xbf = AF32 ? (rblk<256 ? Xf1 + (size_t)rblk*65536
                                      : Xf2 + (size_t)(rblk-256)*65536) : nullptr;
  const u16* Wb = Wt + (size_t)cb*512;
  const int lrow = lane&15, lg = lane>>4, wr = wave>>1, wc = wave&1;
  f32x4 acc[4][4] = {};
  for (int s=0;s<8;s++){
    const int k0 = s<<6;
    #pragma unroll
    for (int q=0;q<4;q++){
      const int i = (wave<<2)+q;
      const int row = (i<<3) + (lane>>3);
      const int cd = (lane&7) ^ (row&7);
      if (AF32){
        const float* src = Xbf + row*512 + k0 + (cd<<3);
        const f32x4 va = *(const f32x4*)src;
        const f32x4 vb = *(const f32x4*)(src+4);
        union{unsigned u[4]; u16x8 v;} U;
        U.u[0]=cvtpk(va[0],va[1]); U.u[1]=cvtpk(va[2],va[3]);
        U.u[2]=cvtpk(vb[0],vb[1]); U.u[3]=cvtpk(vb[2],vb[3]);
        *(u16x8*)((char*)sA + i*1024 + lane*16) = U.v;
      } else {
        gload_lds16(Xb + row*512 + k0 + (cd<<3), sA + i*512);
      }
      gload_lds16(Wb + row*512 + k0 + (cd<<3), sB + i*512);
    }
    __syncthreads();
    #pragma unroll
    for (int kh=0;kh<2;kh++){
      bf16x8 a_[4], b_[4];
      #pragma unroll
      for (int i=0;i<4;i++){
        const int ra = (wr<<6)+(i<<4)+lrow;
        a_[i] = *(const bf16x8*)(sA + ra*64 + ((((kh<<2)+lg)^(ra&7))<<3));
        const int rb = (wc<<6)+(i<<4)+lrow;
        b_[i] = *(const bf16x8*)(sB + rb*64 + ((((kh<<2)+lg)^(rb&7))<<3));
      }
      #pragma unroll
      for (int i=0;i<4;i++)
        #pragma unroll
        for (int j=0;j<4;j++)
          acc[i][j] = __builtin_amdgcn_mfma_f32_16x16x32_bf16(a_[i], b_[j], acc[i][j], 0,0,0);
    }
    __syncthreads();
  }
  #pragma unroll
  for (int j=0;j<4;j++){
    const int colb = (wc<<6) + (j<<4) + lrow;
    const float bv = bias[cb + colb];
    #pragma unroll
    for (int i=0;i<4;i++){
      const int rowb = (wr<<6)+(i<<4)+(lg<<2);
      float v0 = acc[i][j][0]+bv, v1 = acc[i][j][1]+bv;
      float v2 = acc[i][j][2]+bv, v3 = acc[i][j][3]+bv;
      if (ACT){ v0=fmaxf(v0,0.f); v1=fmaxf(v1,0.f); v2=fmaxf(v2,0.f); v3=fmaxf(v3,0.f); }
      unsigned pA = cvtpk(v0,v1), pB = cvtpk(v2,v3);
      smem[(rowb  )*140 + colb] = (u16)pA;
      smem[(rowb+1)*140 + colb] = (u16)(pA>>16);
      smem[(rowb+2)*140 + colb] = (u16)pB;
      smem[(rowb+3)*140 + colb] = (u16)(pB>>16);
    }
  }
  __syncthreads();
  const int chunk = lane&15, rql = lane>>4;
  float ns[8];
  #pragma unroll
  for (int it=0; it<8; it++){
    const int rowb = it*16 + wave*4 + rql;
    u16x8 v8 = *(const u16x8*)(smem + rowb*140 + chunk*8);
    *(u16x8*)(OUT + (size_t)((rblk<<7)+rowb)*512 + cb + chunk*8) = v8;
    if (NORM){
      float s = 0.f;
      #pragma unroll
      for (int e=0;e<8;e++){ float f = b2f(v8[e]); s = fmaf(f,f,s); }
      s += __shfl_xor(s,1); s += __shfl_xor(s,2);
      s += __shfl_xor(s,4); s += __shfl_xor(s,8);
      ns[it] = s;
    }
  }
  if (NORM && chunk==0){
    #pragma unroll
    for (int it=0;it<8;it++)
      NP4[(size_t)(bid&3)*65536 + (rblk<<7) + it*16 + wave*4 + rql] = ns[it];
  }
}

// ---------------------------------------------------------------------------
// pdist_all: 768 blocks. [0,256): C from P; [256,512): Sq planes; [512,768): Sr.
__global__ __launch_bounds__(256) void pdist_all_k(const u16* __restrict__ PQ,
    const float* __restrict__ NP4, const float* __restrict__ cq,
    const float* __restrict__ cr, float* __restrict__ Cm,
    char* __restrict__ SQHL, char* __restrict__ SRHL){
  __shared__ __align__(16) u16 sA[8192];
  __shared__ __align__(16) u16 sB[8192];
  __shared__ float nA[128], nB[128];
  const int tid = threadIdx.x, wave = tid>>6, lane = tid&63;
  const int lrow = lane&15, lg = lane>>4, wr = wave>>1, wc = wave&1;
  const int b = blockIdx.x & 255;

  if (blockIdx.x < 256){
    if (tid < 128){
      const int row = b*128 + tid;
      nA[tid] = NP4[row] + NP4[65536+row] + NP4[131072+row] + NP4[196608+row];
    } else {
      const int row = 32768 + b*128 + (tid-128);
      nB[tid-128] = NP4[row] + NP4[65536+row] + NP4[131072+row] + NP4[196608+row];
    }
    const u16* Ab = PQ + (size_t)b*(128*512);
    const u16* Bb = PQ + (size_t)(32768 + b*128)*512;
    f32x4 acc[4][4] = {};
    for (int s=0;s<8;s++){
      const int k0 = s<<6;
      #pragma unroll
      for (int q=0;q<4;q++){
        const int i = (wave<<2)+q;
        const int row = (i<<3) + (lane>>3);
        const int cd = (lane&7) ^ (row&7);
        gload_lds16(Ab + row*512 + k0 + (cd<<3), sA + i*512);
        gload_lds16(Bb + row*512 + k0 + (cd<<3), sB + i*512);
      }
      __syncthreads();
      #pragma unroll
      for (int kh=0;kh<2;kh++){
        bf16x8 a_[4], b_[4];
        #pragma unroll
        for (int i=0;i<4;i++){
          const int ra = (wr<<6)+(i<<4)+lrow;
          a_[i] = *(const bf16x8*)(sA + ra*64 + ((((kh<<2)+lg)^(ra&7))<<3));
          const int rb = (wc<<6)+(i<<4)+lrow;
          b_[i] = *(const bf16x8*)(sB + rb*64 + ((((kh<<2)+lg)^(rb&7))<<3));
        }
        #pragma unroll
        for (int i=0;i<4;i++)
          #pragma unroll
          for (int j=0;j<4;j++)
            acc[i][j] = __builtin_amdgcn_mfma_f32_16x16x32_bf16(a_[i], b_[j], acc[i][j], 0,0,0);
      }
      __syncthreads();
    }
    #pragma unroll
    for (int j=0;j<4;j++){
      const int col = (wc<<6)+(j<<4)+lrow;
      const float nbv = nB[col];
      #pragma unroll
      for (int i=0;i<4;i++){
        const int row0 = (wr<<6)+(i<<4)+(lg<<2);
        #pragma unroll
        for (int r=0;r<4;r++){
          float n2 = nA[row0+r] + nbv - 2.0f*acc[i][j][r];
          Cm[(size_t)b*16384 + (size_t)(row0+r)*128 + col] = sqrtf(fmaxf(n2, 1e-6f));
        }
      }
    }
  } else {
    const float* Sb = ((blockIdx.x < 512)? cq : cr) + (size_t)b*65536;
    char* SHL = (blockIdx.x < 512)? SQHL : SRHL;
    f32x4 acc[4][4] = {};
    float nacc[4] = {0.f,0.f,0.f,0.f};
    for (int s=0;s<8;s++){
      const int k0 = s<<6;
      #pragma unroll
      for (int q=0;q<4;q++){
        const int i = (wave<<2)+q;
        const int row = (i<<3) + (lane>>3);
        const int cd = (lane&7) ^ (row&7);
        const float* src = Sb + row*512 + k0 + (cd<<3);
        const f32x4 va = *(const f32x4*)src;
        const f32x4 vb = *(const f32x4*)(src+4);
        union{unsigned u[4]; u16x8 v;} U;
        U.u[0]=cvtpk(va[0],va[1]); U.u[1]=cvtpk(va[2],va[3]);
        U.u[2]=cvtpk(vb[0],vb[1]); U.u[3]=cvtpk(vb[2],vb[3]);
        #pragma unroll
        for (int p2=0;p2<4;p2++){
          float f0 = u2f(U.u[p2]<<16), f1 = u2f(U.u[p2]&0xffff0000u);
          nacc[q] = fmaf(f0,f0,nacc[q]);
          nacc[q] = fmaf(f1,f1,nacc[q]);
        }
        *(u16x8*)((char*)sA + i*1024 + lane*16) = U.v;
      }
      __syncthreads();
      #pragma unroll
      for (int kh=0;kh<2;kh++){
        bf16x8 a_[4], b_[4];
        #pragma unroll
        for (int i=0;i<4;i++){
          const int ra = (wr<<6)+(i<<4)+lrow;
          a_[i] = *(const bf16x8*)(sA + ra*64 + ((((kh<<2)+lg)^(ra&7))<<3));
          const int rb = (wc<<6)+(i<<4)+lrow;
          b_[i] = *(const bf16x8*)(sA + rb*64 + ((((kh<<2)+lg)^(rb&7))<<3));
        }
        #pragma unroll
        for (int i=0;i<4;i++)
          #pragma unroll
          for (int j=0;j<4;j++)
            acc[i][j] = __builtin_amdgcn_mfma_f32_16x16x32_bf16(a_[i], b_[j], acc[i][j], 0,0,0);
      }
      __syncthreads();
    }
    #pragma unroll
    for (int q=0;q<4;q++){
      float v = nacc[q];
      v += __shfl_xor(v,1); v += __shfl_xor(v,2); v += __shfl_xor(v,4);
      if ((lane&7)==0) nA[((wave<<2)+q)*8 + (lane>>3)] = v;
    }
    __syncthreads();
    #pragma unroll
    for (int j=0;j<4;j++){
      const int col = (wc<<6)+(j<<4)+lrow;
      const float nbv = nA[col];
      #pragma unroll
      for (int i=0;i<4;i++){
        const int row0 = (wr<<6)+(i<<4)+(lg<<2);
        f32x4 sv;
        #pragma unroll
        for (int r=0;r<4;r++){
          float n2 = nA[row0+r] + nbv - 2.0f*acc[i][j][r];
          sv[r] = sqrtf(fmaxf(n2, 1e-6f));
        }
        u16x4 hi4, lo4;
        split4(sv, &hi4, &lo4);
        const int sa = col*256 + ((((row0>>3)^col)&15)<<4) + ((row0&7)<<1);
        char* base = SHL + (size_t)b*65536;
        *(u16x4*)(base + sa) = hi4;
        *(u16x4*)(base + 32768 + sa) = lo4;
      }
    }
  }
}

// ---------------------------------------------------------------------------
// 5-iter FGW loop, 512 threads/block, base-2 log-domain Sinkhorn.
// lk exchange via linear XOR-slotted buffer; Sr prefetched during Sinkhorn
// (gload_lds); Sq prefetched during phase A via T14 reg-staging.
__global__ __launch_bounds__(512,1) void fgw_loop_k(
    const char* __restrict__ SQHL, const char* __restrict__ SRHL,
    const float* __restrict__ C_g,
    const float* __restrict__ MU, const float* __restrict__ NU,
    const float* __restrict__ LMU2, const float* __restrict__ LNU2,
    const float* __restrict__ log_eps,
    float* __restrict__ T_out, float* __restrict__ cost_out, float* __restrict__ sim_out)
{
  __shared__ __align__(16) char bufT[65536];
  __shared__ __align__(16) char bufS[65536];
  __shared__ __align__(16) float avs[128], bvs[128], t1s[128], t2s[128];
  __shared__ __align__(16) float lus[128], lvs[128];
  __shared__ float redc[8];

  const int b = blockIdx.x, tid = threadIdx.x;
  const int w = tid>>6, lane = tid&63, l15 = lane&15, lg = lane>>4;
  const char* SqHLb = SQHL + (size_t)b*65536;
  const char* SrHLb = SRHL + (size_t)b*65536;
  const float* Cb   = C_g + (size_t)b*16384;
  const float* MUb  = MU + b*128;
  const float* NUb  = NU + b*128;

  float eps = __expf(log_eps[0]); eps = fminf(fmaxf(eps,0.01f),0.5f);
  const float rho = 0.1f/(0.1f+eps);
  const float hscale = 0.5f*1.4426950408889634f/eps;

  const int kR = 16*w + l15;
  const int n0 = 16*w + 4*lg;
  const float lmu2R = LMU2[b*128+kR];
  const float lnu2C = LNU2[b*128+kR];

  const int rowA256 = (16*w + l15)*256;
  const int glo2 = lg ^ (l15 & 3);
  const int ghi2 = l15 & 12;
  const int wtail = l15*256 + ((((2*w + (lg>>1)) ^ l15)&15)<<4) + ((lg&1)<<3);
  const int slotW = lg*16 + (l15^lg);

  f32x4 Cf2[8];
  #pragma unroll
  for (int kt=0;kt<8;kt++)
    Cf2[kt] = -hscale * (*(const f32x4*)(Cb + (size_t)(16*kt+l15)*128 + n0));

  f32x4 lkR[8], lkC[8];
  float luR = 0.f, lvC = 0.f;

  #pragma unroll
  for (int r2=0;r2<8;r2++)
    gload_lds16(SrHLb + r2*8192 + tid*16, bufS + r2*8192 + tid*16);

  for (int outer=0; outer<5; outer++){
    // ---- P0: T planes + avs; bvs via closed form
    {
      f32x4 avp = {0.f,0.f,0.f,0.f};
      #pragma unroll
      for (int q=0;q<8;q++){
        f32x4 TR;
        if (outer==0){
          const f32x4 nu4 = *(const f32x4*)(NUb + 16*q + 4*lg);
          TR = MUb[kR]*nu4;
        } else {
          const f32x4 lv4 = *(const f32x4*)&lvs[16*q + 4*lg];
          #pragma unroll
          for (int e=0;e<4;e++) TR[e] = exp2f(lkR[q][e] + luR + lv4[e]);
        }
        u16x4 hi4, lo4;
        split4(TR, &hi4, &lo4);
        const int sa = kR*256 + ((((2*q+(lg>>1)) ^ l15)&15)<<4) + ((lg&1)<<3);
        *(u16x4*)(bufT + sa) = hi4;
        *(u16x4*)(bufT + 32768 + sa) = lo4;
        avp += TR;
      }
      float av = avp[0]+avp[1]+avp[2]+avp[3];
      av += __shfl_xor(av,16); av += __shfl_xor(av,32);
      if (lg==0){
        avs[kR] = av;
        bvs[kR] = (outer==0) ? NUb[kR] : exp2f(lnu2C - 10.f*eps*lvC);
      }
    }
    __syncthreads();

    // ---- P1: issue Sq reg-loads (T14: hide under phase A); t2; phase A MFMA
    f32x4 sqr[8];
    #pragma unroll
    for (int r2=0;r2<8;r2++)
      sqr[r2] = *(const f32x4*)(SqHLb + r2*8192 + tid*16);
    {
      const int p = tid>>2, sub = tid&3;
      float s2 = 0.f;
      #pragma unroll
      for (int gg=0; gg<4; gg++){
        const int g = 4*sub+gg;
        const int off = p*256 + (((g ^ (p&15))&15)<<4);
        const u16x8 h8 = *(const u16x8*)(bufS + off);
        const u16x8 l8 = *(const u16x8*)(bufS + 32768 + off);
        const f32x4 bva = *(const f32x4*)&bvs[8*g];
        const f32x4 bvb = *(const f32x4*)&bvs[8*g+4];
        #pragma unroll
        for (int e=0;e<4;e++){
          float x = b2f(h8[e]) + b2f(l8[e]);
          s2 = fmaf(bva[e], x*x, s2);
          float y2 = b2f(h8[4+e]) + b2f(l8[4+e]);
          s2 = fmaf(bvb[e], y2*y2, s2);
        }
      }
      s2 += __shfl_xor(s2,1); s2 += __shfl_xor(s2,2);
      if (sub==0) t2s[p] = s2;
    }
    f32x4 acc1[8] = {};
    #pragma unroll
    for (int qt=0;qt<4;qt++){
      const int colOff = (((4*qt) ^ ghi2) | glo2) << 4;
      const bf16x8 ahi = *(const bf16x8*)(bufT + rowA256 + colOff);
      const bf16x8 alo = *(const bf16x8*)(bufT + 32768 + rowA256 + colOff);
      const int bbase = l15*256 + colOff;
      #pragma unroll
      for (int nt=0;nt<8;nt++){
        const bf16x8 bhi = *(const bf16x8*)(bufS + nt*4096 + bbase);
        const bf16x8 blo = *(const bf16x8*)(bufS + 32768 + nt*4096 + bbase);
        acc1[nt] = __builtin_amdgcn_mfma_f32_16x16x32_bf16(ahi, bhi, acc1[nt], 0,0,0);
        acc1[nt] = __builtin_amdgcn_mfma_f32_16x16x32_bf16(ahi, blo, acc1[nt], 0,0,0);
        acc1[nt] = __builtin_amdgcn_mfma_f32_16x16x32_bf16(alo, bhi, acc1[nt], 0,0,0);
      }
    }
    __syncthreads();

    // ---- P2: write prefetched Sq regs -> bufS; write TSr^T planes -> bufT
    #pragma unroll
    for (int r2=0;r2<8;r2++)
      *(f32x4*)(bufS + r2*8192 + tid*16) = sqr[r2];
    #pragma unroll
    for (int nt=0;nt<8;nt++){
      u16x4 hi4, lo4;
      split4(acc1[nt], &hi4, &lo4);
      const int sa = nt*4096 + wtail;
      *(u16x4*)(bufT + sa) = hi4;
      *(u16x4*)(bufT + 32768 + sa) = lo4;
    }
    __syncthreads();

    // ---- P3: t1 from Sq planes + avs; phase B MFMA
    {
      const int p = tid>>2, sub = tid&3;
      float s1 = 0.f;
      #pragma unroll
      for (int gg=0; gg<4; gg++){
        const int g = 4*sub+gg;
        const int off = p*256 + (((g ^ (p&15))&15)<<4);
        const u16x8 h8 = *(const u16x8*)(bufS + off);
        const u16x8 l8 = *(const u16x8*)(bufS + 32768 + off);
        const f32x4 ava = *(const f32x4*)&avs[8*g];
        const f32x4 avb = *(const f32x4*)&avs[8*g+4];
        #pragma unroll
        for (int e=0;e<4;e++){
          float x = b2f(h8[e]) + b2f(l8[e]);
          s1 = fmaf(ava[e], x*x, s1);
          float y2 = b2f(h8[4+e]) + b2f(l8[4+e]);
          s1 = fmaf(avb[e], y2*y2, s1);
        }
      }
      s1 += __shfl_xor(s1,1); s1 += __shfl_xor(s1,2);
      if (sub==0) t1s[p] = s1;
    }
    f32x4 acc2[8] = {};
    #pragma unroll
    for (int qt=0;qt<4;qt++){
      const int colOff = (((4*qt) ^ ghi2) | glo2) << 4;
      const bf16x8 ahi = *(const bf16x8*)(bufT + rowA256 + colOff);
      const bf16x8 alo = *(const bf16x8*)(bufT + 32768 + rowA256 + colOff);
      const int bbase = l15*256 + colOff;
      #pragma unroll
      for (int kt=0;kt<8;kt++){
        const bf16x8 bhi = *(const bf16x8*)(bufS + kt*4096 + bbase);
        const bf16x8 blo = *(const bf16x8*)(bufS + 32768 + kt*4096 + bbase);
        acc2[kt] = __builtin_amdgcn_mfma_f32_16x16x32_bf16(ahi, bhi, acc2[kt], 0,0,0);
        acc2[kt] = __builtin_amdgcn_mfma_f32_16x16x32_bf16(ahi, blo, acc2[kt], 0,0,0);
        acc2[kt] = __builtin_amdgcn_mfma_f32_16x16x32_bf16(alo, bhi, acc2[kt], 0,0,0);
      }
    }
    __syncthreads();

    // ---- P4: prefetch next Sr (gload, hidden under Sinkhorn); lk build + exchange
    if (outer<4){
      #pragma unroll
      for (int r2=0;r2<8;r2++)
        gload_lds16(SrHLb + r2*8192 + tid*16, bufS + r2*8192 + tid*16);
    }
    f32x4 lkf[8];
    {
      const f32x4 t24 = *(const f32x4*)&t2s[n0];
      #pragma unroll
      for (int kt=0;kt<8;kt++){
        const float t1v = t1s[16*kt+l15];
        lkf[kt] = Cf2[kt] + hscale*(2.0f*acc2[kt] - t1v - t24);
      }
    }
    #pragma unroll
    for (int kt=0;kt<8;kt++)
      *(f32x4*)(bufT + (((kt*8+w)*64 + slotW)<<4)) = lkf[kt];
    lds_bar();
    #pragma unroll
    for (int q=0;q<8;q++)
      lkR[q] = *(const f32x4*)(bufT + (((w*8+q)*64 + slotW)<<4));
    #pragma unroll
    for (int q=0;q<8;q++){
      #pragma unroll
      for (int e=0;e<4;e++){
        const int slotC = (l15>>2)*16 + ((4*lg+e) ^ (l15>>2));
        lkC[q][e] = *(const float*)(bufT + (((q*8+w)*64 + slotC)<<4) + ((l15&3)<<2));
      }
    }

    // ---- Sinkhorn: 10 iterations, base-2, lgkm-only barriers
    for (int it=0; it<10; it++){
      f32x4 y[8];
      #pragma unroll
      for (int q=0;q<8;q++){
        y[q] = lkR[q];
        if (it) y[q] += *(const f32x4*)&lvs[16*q+4*lg];
      }
      f32x4 m4 = vmax4(vmax4(vmax4(y[0],y[1]),vmax4(y[2],y[3])),
                       vmax4(vmax4(y[4],y[5]),vmax4(y[6],y[7])));
      float mx = fmaxf(fmaxf(m4[0],m4[1]), fmaxf(m4[2],m4[3]));
      mx = fmaxf(mx,__shfl_xor(mx,16)); mx = fmaxf(mx,__shfl_xor(mx,32));
      f32x4 s4 = {0.f,0.f,0.f,0.f};
      #pragma unroll
      for (int q=0;q<8;q++){
        #pragma unroll
        for (int e=0;e<4;e++) s4[e] += exp2f(y[q][e]-mx);
      }
      float s = s4[0]+s4[1]+s4[2]+s4[3];
      s += __shfl_xor(s,16); s += __shfl_xor(s,32);
      luR = rho*(lmu2R - (mx + __log2f(s)));
      if (lg==0) lus[kR] = luR;
      lds_bar();
      #pragma unroll
      for (int q=0;q<8;q++)
        y[q] = lkC[q] + *(const f32x4*)&lus[16*q+4*lg];
      m4 = vmax4(vmax4(vmax4(y[0],y[1]),vmax4(y[2],y[3])),
                 vmax4(vmax4(y[4],y[5]),vmax4(y[6],y[7])));
      mx = fmaxf(fmaxf(m4[0],m4[1]), fmaxf(m4[2],m4[3]));
      mx = fmaxf(mx,__shfl_xor(mx,16)); mx = fmaxf(mx,__shfl_xor(mx,32));
      s4 = (f32x4){0.f,0.f,0.f,0.f};
      #pragma unroll
      for (int q=0;q<8;q++){
        #pragma unroll
        for (int e=0;e<4;e++) s4[e] += exp2f(y[q][e]-mx);
      }
      s = s4[0]+s4[1]+s4[2]+s4[3];
      s += __shfl_xor(s,16); s += __shfl_xor(s,32);
      lvC = rho*(lnu2C - (mx + __log2f(s)));
      if (lg==0) lvs[kR] = lvC;
      lds_bar();
    }

    if (outer==4){
      float cp = 0.f;
      float* Tb = T_out + (size_t)b*16384;
      #pragma unroll
      for (int q=0;q<8;q++){
        const f32x4 lv4 = *(const f32x4*)&lvs[16*q+4*lg];
        f32x4 t;
        #pragma unroll
        for (int e=0;e<4;e++) t[e] = exp2f(lkR[q][e] + luR + lv4[e]);
        *(f32x4*)(Tb + kR*128 + 16*q + 4*lg) = t;
        const f32x4 pr = t*lkR[q];
        cp += pr[0]+pr[1]+pr[2]+pr[3];
      }
      cp *= -eps*0.6931471805599453f;
      #pragma unroll
      for (int off=1;off<64;off<<=1) cp += __shfl_xor(cp, off);
      if (lane==0) redc[w] = cp;
      __syncthreads();
      if (tid==0){
        float tot = 0.f;
        #pragma unroll
        for (int w2=0;w2<8;w2++) tot += redc[w2];
        cost_out[b] = tot;
        sim_out[b]  = 1.0f/(1.0f + __expf(tot));
      }
    }
  }
}

// ---------------------------------------------------------------------------
extern "C" void kernel_launch(void* const* d_in, const int* in_sizes, int n_in,
                              void* d_out, int out_size, void* d_ws, size_t ws_size,
                              hipStream_t stream){
  const float* sq      = (const float*)d_in[0];
  const float* sr      = (const float*)d_in[1];
  const float* mask_q  = (const float*)d_in[2];
  const float* mask_r  = (const float*)d_in[3];
  const float* cq      = (const float*)d_in[4];
  const float* cr      = (const float*)d_in[5];
  const float* W1      = (const float*)d_in[6];
  const float* b1      = (const float*)d_in[7];
  const float* W2      = (const float*)d_in[8];
  const float* b2      = (const float*)d_in[9];
  const float* log_eps = (const float*)d_in[10];

  float* out  = (float*)d_out;
  float* sim  = out;                 // [256]
  float* Tm   = out + 256;           // [256][128][128]
  float* Cm   = Tm + 4194304;        // [256][128][128]
  float* cost = Cm + 4194304;        // [256]

  char* ws = (char*)d_ws;
  size_t off = 0;
  auto alloc = [&](size_t bytes)->void*{ void* p = ws + off; off += (bytes+255)&~(size_t)255; return p; };
  u16*   PQ  = (u16*)  alloc(67108864);   // P bf16 (65536x512); later loop planes
  u16*   HQ  = (u16*)  alloc(67108864);   // hidden H bf16 (65536x512)
  u16*   W1T = (u16*)  alloc(524288);
  u16*   W2T = (u16*)  alloc(524288);
  float* NP4 = (float*)alloc(1048576);    // per-cb row-norm partials [4][65536]
  float* LMU = (float*)alloc(131072);
  float* LNU = (float*)alloc(131072);
  float* MUA = (float*)alloc(131072);
  float* NUA = (float*)alloc(131072);
  (void)ws_size; (void)in_sizes; (void)n_in; (void)out_size;

  char* SQHL = (char*)PQ;                  // 16MB bf16 hi/lo Sq planes
  char* SRHL = (char*)PQ + 16777216;       // 16MB bf16 hi/lo Sr planes

  prologue_k<<<2176,256,0,stream>>>(W1, W2, W1T, W2T, mask_q, mask_r,
                                    LMU, LNU, MUA, NUA);
  gemm_k<1,0,1><<<2048,256,0,stream>>>(nullptr, sq, sr, W1T, b1, HQ, nullptr);
  gemm_k<0,1,0><<<2048,256,0,stream>>>(HQ, nullptr, nullptr, W2T, b2, PQ, NP4);
  pdist_all_k<<<768,256,0,stream>>>(PQ, NP4, cq, cr, Cm, SQHL, SRHL);
  fgw_loop_k<<<256,512,0,stream>>>(SQHL, SRHL, Cm, MUA, NUA, LMU, LNU,
                                   log_eps, Tm, cost, sim);
}

// Round 14
// 391.064 us; speedup vs baseline: 1.0672x; 1.0207x over previous
//
#include <hip/hip_runtime.h>
#include <math.h>

typedef unsigned short u16;
typedef __attribute__((ext_vector_type(4))) float f32x4;
typedef __attribute__((ext_vector_type(8))) short bf16x8;
typedef __attribute__((ext_vector_type(4))) unsigned short u16x4;
typedef __attribute__((ext_vector_type(8))) unsigned short u16x8;

#define DEVI static __device__ __forceinline__

DEVI float b2f(u16 u){ union{float f; unsigned i;} v; v.i = ((unsigned)u)<<16; return v.f; }
DEVI u16 f2b(float f){ union{float f; unsigned i;} v; v.f=f;
  unsigned r = v.i + 0x7fffu + ((v.i>>16)&1u); return (u16)(r>>16); }
DEVI float u2f(unsigned u){ union{unsigned i; float f;} v; v.i=u; return v.f; }

// packed f32->2xbf16 (gfx950 native; no builtin -> inline asm, T12 recipe)
DEVI unsigned cvtpk(float a, float b){
  unsigned r;
  asm("v_cvt_pk_bf16_f32 %0, %1, %2" : "=v"(r) : "v"(a), "v"(b));
  return r;
}

// split f32x4 -> hi/lo bf16x4 via cvt_pk
DEVI void split4(const f32x4 x, u16x4* hi4, u16x4* lo4){
  unsigned h0 = cvtpk(x[0], x[1]);
  unsigned h1 = cvtpk(x[2], x[3]);
  unsigned l0 = cvtpk(x[0]-u2f(h0<<16), x[1]-u2f(h0&0xffff0000u));
  unsigned l1 = cvtpk(x[2]-u2f(h1<<16), x[3]-u2f(h1&0xffff0000u));
  union{unsigned u[2]; u16x4 v;} H,L;
  H.u[0]=h0; H.u[1]=h1; L.u[0]=l0; L.u[1]=l1;
  *hi4 = H.v; *lo4 = L.v;
}

DEVI void gload_lds16(const void* g, void* l){
  __builtin_amdgcn_global_load_lds((const __attribute__((address_space(1))) void*)g,
                                   (__attribute__((address_space(3))) void*)l, 16, 0, 0);
}

// LDS-only barrier: waits DS ops, does NOT drain vmcnt (keeps prefetch in flight)
DEVI void lds_bar(){ asm volatile("s_waitcnt lgkmcnt(0)\n\ts_barrier" ::: "memory"); }

DEVI f32x4 vmax4(f32x4 a, f32x4 b){
  f32x4 r; r[0]=fmaxf(a[0],b[0]); r[1]=fmaxf(a[1],b[1]);
  r[2]=fmaxf(a[2],b[2]); r[3]=fmaxf(a[3],b[3]); return r;
}

// ---------------------------------------------------------------------------
// Merged prologue: blocks [0,2048): W1/W2 -> bf16 [c][k]; blocks [2048,2176):
// mu/nu + base-2 logs (2 batches per 256-thread block).
__global__ void prologue_k(const float* __restrict__ W1, const float* __restrict__ W2,
                           u16* __restrict__ W1T, u16* __restrict__ W2T,
                           const float* __restrict__ mask_q, const float* __restrict__ mask_r,
                           float* __restrict__ lmu2, float* __restrict__ lnu2,
                           float* __restrict__ mu, float* __restrict__ nu){
  const int blk = blockIdx.x;
  if (blk < 2048){
    const float* W = (blk<1024)? W1 : W2;
    u16* Wt = (blk<1024)? W1T : W2T;
    int id = (blk&1023)*256 + threadIdx.x;
    int k = id>>9, c = id&511;
    Wt[c*512 + k] = f2b(W[id]);
  } else {
    __shared__ float red[2][4];
    const int h = threadIdx.x>>7, t = threadIdx.x&127;
    const int b = (blk-2048)*2 + h;
    float mq = mask_q[b*128+t], mr = mask_r[b*128+t];
    float s1 = mq, s2 = mr;
    #pragma unroll
    for (int off=1;off<64;off<<=1){ s1 += __shfl_xor(s1,off); s2 += __shfl_xor(s2,off); }
    if ((t&63)==0){ red[h][(t>>6)&1] = s1; red[h][2+((t>>6)&1)] = s2; }
    __syncthreads();
    float sumq = red[h][0]+red[h][1], sumr = red[h][2]+red[h][3];
    float muv = mq/(sumq+1e-8f), nuv = mr/(sumr+1e-8f);
    lmu2[b*128+t] = __log2f(fmaxf(muv,1e-8f));
    lnu2[b*128+t] = __log2f(fmaxf(nuv,1e-8f));
    mu[b*128+t] = muv;
    nu[b*128+t] = nuv;
  }
}

// ---------------------------------------------------------------------------
// GEMM, 256x128 tile, 512 threads (8 waves, 64x64 out each), BK=64.
// OUT[r][c] = act(sum_k X[r][k]*W[k][c] + bias[c]); Wt bf16 [c][k].
// AF32: A-tile reg-staged from f32 via cvt_pk. NORM: per-cb partials to NP4.
// Epilogue via LDS transpose in two 128-row halves.
template<int ACT, int NORM, int AF32>
__global__ __launch_bounds__(512) void gemm_k(const u16* __restrict__ X,
    const float* __restrict__ Xf1, const float* __restrict__ Xf2,
    const u16* __restrict__ Wt, const float* __restrict__ bias, u16* __restrict__ OUT,
    float* __restrict__ NP4){
  __shared__ __align__(16) u16 smem[24576];        // sA 32KB | sB 16KB ; epi reuses 35.8KB
  u16* sA = smem;                                   // 256 x 64
  u16* sB = smem + 16384;                           // 128 x 64
  const int tid = threadIdx.x, wave = tid>>6, lane = tid&63;
  const int bid = (blockIdx.x&7)*128 + (blockIdx.x>>3);   // 1024 blocks, XCD-chunked
  const int rblk = bid>>2, cb = (bid&3)<<7;
  const u16* Xb = AF32 ? nullptr : (X + (size_t)rblk*131072);
  const float* Xbf = AF32 ? (rblk<128 ? Xf1 + (size_t)rblk*131072
                                      : Xf2 + (size_t)(rblk-128)*131072) : nullptr;
  const u16* Wb = Wt + (size_t)cb*512;
  const int lrow = lane&15, lg = lane>>4, wr = wave>>1, wc = wave&1;
  f32x4 acc[4][4] = {};
  for (int s=0;s<8;s++){
    const int k0 = s<<6;
    // B staging: 2 rounds/thread (gload)
    #pragma unroll
    for (int q=0;q<2;q++){
      const int g = (wave*2+q)*64 + lane;
      const int row = g>>3;
      const int cd = (g&7) ^ (row&7);
      gload_lds16(Wb + row*512 + k0 + (cd<<3), (char*)sB + (wave*2+q)*1024 + lane*16);
    }
    // A staging: 4 rounds/thread
    #pragma unroll
    for (int q=0;q<4;q++){
      const int g = (wave*4+q)*64 + lane;
      const int row = g>>3;
      const int cd = (g&7) ^ (row&7);
      if (AF32){
        const float* src = Xbf + row*512 + k0 + (cd<<3);
        const f32x4 va = *(const f32x4*)src;
        const f32x4 vb = *(const f32x4*)(src+4);
        union{unsigned u[4]; u16x8 v;} U;
        U.u[0]=cvtpk(va[0],va[1]); U.u[1]=cvtpk(va[2],va[3]);
        U.u[2]=cvtpk(vb[0],vb[1]); U.u[3]=cvtpk(vb[2],vb[3]);
        *(u16x8*)((char*)sA + (wave*4+q)*1024 + lane*16) = U.v;
      } else {
        gload_lds16(Xb + row*512 + k0 + (cd<<3), (char*)sA + (wave*4+q)*1024 + lane*16);
      }
    }
    __syncthreads();
    #pragma unroll
    for (int kh=0;kh<2;kh++){
      bf16x8 a_[4], b_[4];
      #pragma unroll
      for (int i=0;i<4;i++){
        const int ra = (wr<<6)+(i<<4)+lrow;
        a_[i] = *(const bf16x8*)(sA + ra*64 + ((((kh<<2)+lg)^(ra&7))<<3));
        const int rb = (wc<<6)+(i<<4)+lrow;
        b_[i] = *(const bf16x8*)(sB + rb*64 + ((((kh<<2)+lg)^(rb&7))<<3));
      }
      #pragma unroll
      for (int i=0;i<4;i++)
        #pragma unroll
        for (int j=0;j<4;j++)
          acc[i][j] = __builtin_amdgcn_mfma_f32_16x16x32_bf16(a_[i], b_[j], acc[i][j], 0,0,0);
    }
    __syncthreads();
  }
  // ---- epilogue: two 128-row halves through a 128x140 LDS transpose buffer
  #pragma unroll
  for (int h=0; h<2; h++){
    if ((wave>>2) == h){
      #pragma unroll
      for (int j=0;j<4;j++){
        const int colb = (wc<<6) + (j<<4) + lrow;
        const float bv = bias[cb + colb];
        #pragma unroll
        for (int i=0;i<4;i++){
          const int lr = ((wr&1)<<6)+(i<<4)+(lg<<2);
          float v0 = acc[i][j][0]+bv, v1 = acc[i][j][1]+bv;
          float v2 = acc[i][j][2]+bv, v3 = acc[i][j][3]+bv;
          if (ACT){ v0=fmaxf(v0,0.f); v1=fmaxf(v1,0.f); v2=fmaxf(v2,0.f); v3=fmaxf(v3,0.f); }
          unsigned pA = cvtpk(v0,v1), pB = cvtpk(v2,v3);
          smem[(lr  )*140 + colb] = (u16)pA;
          smem[(lr+1)*140 + colb] = (u16)(pA>>16);
          smem[(lr+2)*140 + colb] = (u16)pB;
          smem[(lr+3)*140 + colb] = (u16)(pB>>16);
        }
      }
    }
    __syncthreads();
    const int chunk = tid&15, rsub = tid>>4;    // 32 rows per round
    #pragma unroll
    for (int it=0; it<4; it++){
      const int lr = it*32 + rsub;
      u16x8 v8 = *(const u16x8*)(smem + lr*140 + chunk*8);
      *(u16x8*)(OUT + (size_t)(rblk*256 + h*128 + lr)*512 + cb + chunk*8) = v8;
      if (NORM){
        float sn = 0.f;
        #pragma unroll
        for (int e=0;e<8;e++){ float f = b2f(v8[e]); sn = fmaf(f,f,sn); }
        sn += __shfl_xor(sn,1); sn += __shfl_xor(sn,2);
        sn += __shfl_xor(sn,4); sn += __shfl_xor(sn,8);
        if (chunk==0)
          NP4[(size_t)(bid&3)*65536 + rblk*256 + h*128 + lr] = sn;
      }
    }
    __syncthreads();
  }
}

// ---------------------------------------------------------------------------
// pdist_all: 768 blocks. [0,256): C from P; [256,512): Sq planes; [512,768): Sr.
__global__ __launch_bounds__(256) void pdist_all_k(const u16* __restrict__ PQ,
    const float* __restrict__ NP4, const float* __restrict__ cq,
    const float* __restrict__ cr, float* __restrict__ Cm,
    char* __restrict__ SQHL, char* __restrict__ SRHL){
  __shared__ __align__(16) u16 sA[8192];
  __shared__ __align__(16) u16 sB[8192];
  __shared__ float nA[128], nB[128];
  const int tid = threadIdx.x, wave = tid>>6, lane = tid&63;
  const int lrow = lane&15, lg = lane>>4, wr = wave>>1, wc = wave&1;
  const int b = blockIdx.x & 255;

  if (blockIdx.x < 256){
    if (tid < 128){
      const int row = b*128 + tid;
      nA[tid] = NP4[row] + NP4[65536+row] + NP4[131072+row] + NP4[196608+row];
    } else {
      const int row = 32768 + b*128 + (tid-128);
      nB[tid-128] = NP4[row] + NP4[65536+row] + NP4[131072+row] + NP4[196608+row];
    }
    const u16* Ab = PQ + (size_t)b*(128*512);
    const u16* Bb = PQ + (size_t)(32768 + b*128)*512;
    f32x4 acc[4][4] = {};
    for (int s=0;s<8;s++){
      const int k0 = s<<6;
      #pragma unroll
      for (int q=0;q<4;q++){
        const int i = (wave<<2)+q;
        const int row = (i<<3) + (lane>>3);
        const int cd = (lane&7) ^ (row&7);
        gload_lds16(Ab + row*512 + k0 + (cd<<3), sA + i*512);
        gload_lds16(Bb + row*512 + k0 + (cd<<3), sB + i*512);
      }
      __syncthreads();
      #pragma unroll
      for (int kh=0;kh<2;kh++){
        bf16x8 a_[4], b_[4];
        #pragma unroll
        for (int i=0;i<4;i++){
          const int ra = (wr<<6)+(i<<4)+lrow;
          a_[i] = *(const bf16x8*)(sA + ra*64 + ((((kh<<2)+lg)^(ra&7))<<3));
          const int rb = (wc<<6)+(i<<4)+lrow;
          b_[i] = *(const bf16x8*)(sB + rb*64 + ((((kh<<2)+lg)^(rb&7))<<3));
        }
        #pragma unroll
        for (int i=0;i<4;i++)
          #pragma unroll
          for (int j=0;j<4;j++)
            acc[i][j] = __builtin_amdgcn_mfma_f32_16x16x32_bf16(a_[i], b_[j], acc[i][j], 0,0,0);
      }
      __syncthreads();
    }
    #pragma unroll
    for (int j=0;j<4;j++){
      const int col = (wc<<6)+(j<<4)+lrow;
      const float nbv = nB[col];
      #pragma unroll
      for (int i=0;i<4;i++){
        const int row0 = (wr<<6)+(i<<4)+(lg<<2);
        #pragma unroll
        for (int r=0;r<4;r++){
          float n2 = nA[row0+r] + nbv - 2.0f*acc[i][j][r];
          Cm[(size_t)b*16384 + (size_t)(row0+r)*128 + col] = sqrtf(fmaxf(n2, 1e-6f));
        }
      }
    }
  } else {
    const float* Sb = ((blockIdx.x < 512)? cq : cr) + (size_t)b*65536;
    char* SHL = (blockIdx.x < 512)? SQHL : SRHL;
    f32x4 acc[4][4] = {};
    float nacc[4] = {0.f,0.f,0.f,0.f};
    for (int s=0;s<8;s++){
      const int k0 = s<<6;
      #pragma unroll
      for (int q=0;q<4;q++){
        const int i = (wave<<2)+q;
        const int row = (i<<3) + (lane>>3);
        const int cd = (lane&7) ^ (row&7);
        const float* src = Sb + row*512 + k0 + (cd<<3);
        const f32x4 va = *(const f32x4*)src;
        const f32x4 vb = *(const f32x4*)(src+4);
        union{unsigned u[4]; u16x8 v;} U;
        U.u[0]=cvtpk(va[0],va[1]); U.u[1]=cvtpk(va[2],va[3]);
        U.u[2]=cvtpk(vb[0],vb[1]); U.u[3]=cvtpk(vb[2],vb[3]);
        #pragma unroll
        for (int p2=0;p2<4;p2++){
          float f0 = u2f(U.u[p2]<<16), f1 = u2f(U.u[p2]&0xffff0000u);
          nacc[q] = fmaf(f0,f0,nacc[q]);
          nacc[q] = fmaf(f1,f1,nacc[q]);
        }
        *(u16x8*)((char*)sA + i*1024 + lane*16) = U.v;
      }
      __syncthreads();
      #pragma unroll
      for (int kh=0;kh<2;kh++){
        bf16x8 a_[4], b_[4];
        #pragma unroll
        for (int i=0;i<4;i++){
          const int ra = (wr<<6)+(i<<4)+lrow;
          a_[i] = *(const bf16x8*)(sA + ra*64 + ((((kh<<2)+lg)^(ra&7))<<3));
          const int rb = (wc<<6)+(i<<4)+lrow;
          b_[i] = *(const bf16x8*)(sA + rb*64 + ((((kh<<2)+lg)^(rb&7))<<3));
        }
        #pragma unroll
        for (int i=0;i<4;i++)
          #pragma unroll
          for (int j=0;j<4;j++)
            acc[i][j] = __builtin_amdgcn_mfma_f32_16x16x32_bf16(a_[i], b_[j], acc[i][j], 0,0,0);
      }
      __syncthreads();
    }
    #pragma unroll
    for (int q=0;q<4;q++){
      float v = nacc[q];
      v += __shfl_xor(v,1); v += __shfl_xor(v,2); v += __shfl_xor(v,4);
      if ((lane&7)==0) nA[((wave<<2)+q)*8 + (lane>>3)] = v;
    }
    __syncthreads();
    #pragma unroll
    for (int j=0;j<4;j++){
      const int col = (wc<<6)+(j<<4)+lrow;
      const float nbv = nA[col];
      #pragma unroll
      for (int i=0;i<4;i++){
        const int row0 = (wr<<6)+(i<<4)+(lg<<2);
        f32x4 sv;
        #pragma unroll
        for (int r=0;r<4;r++){
          float n2 = nA[row0+r] + nbv - 2.0f*acc[i][j][r];
          sv[r] = sqrtf(fmaxf(n2, 1e-6f));
        }
        u16x4 hi4, lo4;
        split4(sv, &hi4, &lo4);
        const int sa = col*256 + ((((row0>>3)^col)&15)<<4) + ((row0&7)<<1);
        char* base = SHL + (size_t)b*65536;
        *(u16x4*)(base + sa) = hi4;
        *(u16x4*)(base + 32768 + sa) = lo4;
      }
    }
  }
}

// ---------------------------------------------------------------------------
// 5-iter FGW loop, 512 threads/block, base-2 log-domain Sinkhorn.
// (unchanged from R12 — verified)
__global__ __launch_bounds__(512,1) void fgw_loop_k(
    const char* __restrict__ SQHL, const char* __restrict__ SRHL,
    const float* __restrict__ C_g,
    const float* __restrict__ MU, const float* __restrict__ NU,
    const float* __restrict__ LMU2, const float* __restrict__ LNU2,
    const float* __restrict__ log_eps,
    float* __restrict__ T_out, float* __restrict__ cost_out, float* __restrict__ sim_out)
{
  __shared__ __align__(16) char bufT[65536];
  __shared__ __align__(16) char bufS[65536];
  __shared__ __align__(16) float avs[128], bvs[128], t1s[128], t2s[128];
  __shared__ __align__(16) float lus[128], lvs[128];
  __shared__ float redc[8];

  const int b = blockIdx.x, tid = threadIdx.x;
  const int w = tid>>6, lane = tid&63, l15 = lane&15, lg = lane>>4;
  const char* SqHLb = SQHL + (size_t)b*65536;
  const char* SrHLb = SRHL + (size_t)b*65536;
  const float* Cb   = C_g + (size_t)b*16384;
  const float* MUb  = MU + b*128;
  const float* NUb  = NU + b*128;

  float eps = __expf(log_eps[0]); eps = fminf(fmaxf(eps,0.01f),0.5f);
  const float rho = 0.1f/(0.1f+eps);
  const float hscale = 0.5f*1.4426950408889634f/eps;

  const int kR = 16*w + l15;
  const int n0 = 16*w + 4*lg;
  const float lmu2R = LMU2[b*128+kR];
  const float lnu2C = LNU2[b*128+kR];

  const int rowA256 = (16*w + l15)*256;
  const int glo2 = lg ^ (l15 & 3);
  const int ghi2 = l15 & 12;
  const int wtail = l15*256 + ((((2*w + (lg>>1)) ^ l15)&15)<<4) + ((lg&1)<<3);
  const int slotW = lg*16 + (l15^lg);

  f32x4 Cf2[8];
  #pragma unroll
  for (int kt=0;kt<8;kt++)
    Cf2[kt] = -hscale * (*(const f32x4*)(Cb + (size_t)(16*kt+l15)*128 + n0));

  f32x4 lkR[8], lkC[8];
  float luR = 0.f, lvC = 0.f;

  #pragma unroll
  for (int r2=0;r2<8;r2++)
    gload_lds16(SrHLb + r2*8192 + tid*16, bufS + r2*8192 + tid*16);

  for (int outer=0; outer<5; outer++){
    // ---- P0: T planes + avs; bvs via closed form
    {
      f32x4 avp = {0.f,0.f,0.f,0.f};
      #pragma unroll
      for (int q=0;q<8;q++){
        f32x4 TR;
        if (outer==0){
          const f32x4 nu4 = *(const f32x4*)(NUb + 16*q + 4*lg);
          TR = MUb[kR]*nu4;
        } else {
          const f32x4 lv4 = *(const f32x4*)&lvs[16*q + 4*lg];
          #pragma unroll
          for (int e=0;e<4;e++) TR[e] = exp2f(lkR[q][e] + luR + lv4[e]);
        }
        u16x4 hi4, lo4;
        split4(TR, &hi4, &lo4);
        const int sa = kR*256 + ((((2*q+(lg>>1)) ^ l15)&15)<<4) + ((lg&1)<<3);
        *(u16x4*)(bufT + sa) = hi4;
        *(u16x4*)(bufT + 32768 + sa) = lo4;
        avp += TR;
      }
      float av = avp[0]+avp[1]+avp[2]+avp[3];
      av += __shfl_xor(av,16); av += __shfl_xor(av,32);
      if (lg==0){
        avs[kR] = av;
        bvs[kR] = (outer==0) ? NUb[kR] : exp2f(lnu2C - 10.f*eps*lvC);
      }
    }
    __syncthreads();

    // ---- P1: issue Sq reg-loads (T14); t2; phase A MFMA
    f32x4 sqr[8];
    #pragma unroll
    for (int r2=0;r2<8;r2++)
      sqr[r2] = *(const f32x4*)(SqHLb + r2*8192 + tid*16);
    {
      const int p = tid>>2, sub = tid&3;
      float s2 = 0.f;
      #pragma unroll
      for (int gg=0; gg<4; gg++){
        const int g = 4*sub+gg;
        const int off = p*256 + (((g ^ (p&15))&15)<<4);
        const u16x8 h8 = *(const u16x8*)(bufS + off);
        const u16x8 l8 = *(const u16x8*)(bufS + 32768 + off);
        const f32x4 bva = *(const f32x4*)&bvs[8*g];
        const f32x4 bvb = *(const f32x4*)&bvs[8*g+4];
        #pragma unroll
        for (int e=0;e<4;e++){
          float x = b2f(h8[e]) + b2f(l8[e]);
          s2 = fmaf(bva[e], x*x, s2);
          float y2 = b2f(h8[4+e]) + b2f(l8[4+e]);
          s2 = fmaf(bvb[e], y2*y2, s2);
        }
      }
      s2 += __shfl_xor(s2,1); s2 += __shfl_xor(s2,2);
      if (sub==0) t2s[p] = s2;
    }
    f32x4 acc1[8] = {};
    #pragma unroll
    for (int qt=0;qt<4;qt++){
      const int colOff = (((4*qt) ^ ghi2) | glo2) << 4;
      const bf16x8 ahi = *(const bf16x8*)(bufT + rowA256 + colOff);
      const bf16x8 alo = *(const bf16x8*)(bufT + 32768 + rowA256 + colOff);
      const int bbase = l15*256 + colOff;
      #pragma unroll
      for (int nt=0;nt<8;nt++){
        const bf16x8 bhi = *(const bf16x8*)(bufS + nt*4096 + bbase);
        const bf16x8 blo = *(const bf16x8*)(bufS + 32768 + nt*4096 + bbase);
        acc1[nt] = __builtin_amdgcn_mfma_f32_16x16x32_bf16(ahi, bhi, acc1[nt], 0,0,0);
        acc1[nt] = __builtin_amdgcn_mfma_f32_16x16x32_bf16(ahi, blo, acc1[nt], 0,0,0);
        acc1[nt] = __builtin_amdgcn_mfma_f32_16x16x32_bf16(alo, bhi, acc1[nt], 0,0,0);
      }
    }
    __syncthreads();

    // ---- P2: write prefetched Sq regs -> bufS; write TSr^T planes -> bufT
    #pragma unroll
    for (int r2=0;r2<8;r2++)
      *(f32x4*)(bufS + r2*8192 + tid*16) = sqr[r2];
    #pragma unroll
    for (int nt=0;nt<8;nt++){
      u16x4 hi4, lo4;
      split4(acc1[nt], &hi4, &lo4);
      const int sa = nt*4096 + wtail;
      *(u16x4*)(bufT + sa) = hi4;
      *(u16x4*)(bufT + 32768 + sa) = lo4;
    }
    __syncthreads();

    // ---- P3: t1 from Sq planes + avs; phase B MFMA
    {
      const int p = tid>>2, sub = tid&3;
      float s1 = 0.f;
      #pragma unroll
      for (int gg=0; gg<4; gg++){
        const int g = 4*sub+gg;
        const int off = p*256 + (((g ^ (p&15))&15)<<4);
        const u16x8 h8 = *(const u16x8*)(bufS + off);
        const u16x8 l8 = *(const u16x8*)(bufS + 32768 + off);
        const f32x4 ava = *(const f32x4*)&avs[8*g];
        const f32x4 avb = *(const f32x4*)&avs[8*g+4];
        #pragma unroll
        for (int e=0;e<4;e++){
          float x = b2f(h8[e]) + b2f(l8[e]);
          s1 = fmaf(ava[e], x*x, s1);
          float y2 = b2f(h8[4+e]) + b2f(l8[4+e]);
          s1 = fmaf(avb[e], y2*y2, s1);
        }
      }
      s1 += __shfl_xor(s1,1); s1 += __shfl_xor(s1,2);
      if (sub==0) t1s[p] = s1;
    }
    f32x4 acc2[8] = {};
    #pragma unroll
    for (int qt=0;qt<4;qt++){
      const int colOff = (((4*qt) ^ ghi2) | glo2) << 4;
      const bf16x8 ahi = *(const bf16x8*)(bufT + rowA256 + colOff);
      const bf16x8 alo = *(const bf16x8*)(bufT + 32768 + rowA256 + colOff);
      const int bbase = l15*256 + colOff;
      #pragma unroll
      for (int kt=0;kt<8;kt++){
        const bf16x8 bhi = *(const bf16x8*)(bufS + kt*4096 + bbase);
        const bf16x8 blo = *(const bf16x8*)(bufS + 32768 + kt*4096 + bbase);
        acc2[kt] = __builtin_amdgcn_mfma_f32_16x16x32_bf16(ahi, bhi, acc2[kt], 0,0,0);
        acc2[kt] = __builtin_amdgcn_mfma_f32_16x16x32_bf16(ahi, blo, acc2[kt], 0,0,0);
        acc2[kt] = __builtin_amdgcn_mfma_f32_16x16x32_bf16(alo, bhi, acc2[kt], 0,0,0);
      }
    }
    __syncthreads();

    // ---- P4: prefetch next Sr; lk build + exchange
    if (outer<4){
      #pragma unroll
      for (int r2=0;r2<8;r2++)
        gload_lds16(SrHLb + r2*8192 + tid*16, bufS + r2*8192 + tid*16);
    }
    f32x4 lkf[8];
    {
      const f32x4 t24 = *(const f32x4*)&t2s[n0];
      #pragma unroll
      for (int kt=0;kt<8;kt++){
        const float t1v = t1s[16*kt+l15];
        lkf[kt] = Cf2[kt] + hscale*(2.0f*acc2[kt] - t1v - t24);
      }
    }
    #pragma unroll
    for (int kt=0;kt<8;kt++)
      *(f32x4*)(bufT + (((kt*8+w)*64 + slotW)<<4)) = lkf[kt];
    lds_bar();
    #pragma unroll
    for (int q=0;q<8;q++)
      lkR[q] = *(const f32x4*)(bufT + (((w*8+q)*64 + slotW)<<4));
    #pragma unroll
    for (int q=0;q<8;q++){
      #pragma unroll
      for (int e=0;e<4;e++){
        const int slotC = (l15>>2)*16 + ((4*lg+e) ^ (l15>>2));
        lkC[q][e] = *(const float*)(bufT + (((q*8+w)*64 + slotC)<<4) + ((l15&3)<<2));
      }
    }

    // ---- Sinkhorn: 10 iterations, base-2, lgkm-only barriers
    for (int it=0; it<10; it++){
      f32x4 y[8];
      #pragma unroll
      for (int q=0;q<8;q++){
        y[q] = lkR[q];
        if (it) y[q] += *(const f32x4*)&lvs[16*q+4*lg];
      }
      f32x4 m4 = vmax4(vmax4(vmax4(y[0],y[1]),vmax4(y[2],y[3])),
                       vmax4(vmax4(y[4],y[5]),vmax4(y[6],y[7])));
      float mx = fmaxf(fmaxf(m4[0],m4[1]), fmaxf(m4[2],m4[3]));
      mx = fmaxf(mx,__shfl_xor(mx,16)); mx = fmaxf(mx,__shfl_xor(mx,32));
      f32x4 s4 = {0.f,0.f,0.f,0.f};
      #pragma unroll
      for (int q=0;q<8;q++){
        #pragma unroll
        for (int e=0;e<4;e++) s4[e] += exp2f(y[q][e]-mx);
      }
      float s = s4[0]+s4[1]+s4[2]+s4[3];
      s += __shfl_xor(s,16); s += __shfl_xor(s,32);
      luR = rho*(lmu2R - (mx + __log2f(s)));
      if (lg==0) lus[kR] = luR;
      lds_bar();
      #pragma unroll
      for (int q=0;q<8;q++)
        y[q] = lkC[q] + *(const f32x4*)&lus[16*q+4*lg];
      m4 = vmax4(vmax4(vmax4(y[0],y[1]),vmax4(y[2],y[3])),
                 vmax4(vmax4(y[4],y[5]),vmax4(y[6],y[7])));
      mx = fmaxf(fmaxf(m4[0],m4[1]), fmaxf(m4[2],m4[3]));
      mx = fmaxf(mx,__shfl_xor(mx,16)); mx = fmaxf(mx,__shfl_xor(mx,32));
      s4 = (f32x4){0.f,0.f,0.f,0.f};
      #pragma unroll
      for (int q=0;q<8;q++){
        #pragma unroll
        for (int e=0;e<4;e++) s4[e] += exp2f(y[q][e]-mx);
      }
      s = s4[0]+s4[1]+s4[2]+s4[3];
      s += __shfl_xor(s,16); s += __shfl_xor(s,32);
      lvC = rho*(lnu2C - (mx + __log2f(s)));
      if (lg==0) lvs[kR] = lvC;
      lds_bar();
    }

    if (outer==4){
      float cp = 0.f;
      float* Tb = T_out + (size_t)b*16384;
      #pragma unroll
      for (int q=0;q<8;q++){
        const f32x4 lv4 = *(const f32x4*)&lvs[16*q+4*lg];
        f32x4 t;
        #pragma unroll
        for (int e=0;e<4;e++) t[e] = exp2f(lkR[q][e] + luR + lv4[e]);
        *(f32x4*)(Tb + kR*128 + 16*q + 4*lg) = t;
        const f32x4 pr = t*lkR[q];
        cp += pr[0]+pr[1]+pr[2]+pr[3];
      }
      cp *= -eps*0.6931471805599453f;
      #pragma unroll
      for (int off=1;off<64;off<<=1) cp += __shfl_xor(cp, off);
      if (lane==0) redc[w] = cp;
      __syncthreads();
      if (tid==0){
        float tot = 0.f;
        #pragma unroll
        for (int w2=0;w2<8;w2++) tot += redc[w2];
        cost_out[b] = tot;
        sim_out[b]  = 1.0f/(1.0f + __expf(tot));
      }
    }
  }
}

// ---------------------------------------------------------------------------
extern "C" void kernel_launch(void* const* d_in, const int* in_sizes, int n_in,
                              void* d_out, int out_size, void* d_ws, size_t ws_size,
                              hipStream_t stream){
  const float* sq      = (const float*)d_in[0];
  const float* sr      = (const float*)d_in[1];
  const float* mask_q  = (const float*)d_in[2];
  const float* mask_r  = (const float*)d_in[3];
  const float* cq      = (const float*)d_in[4];
  const float* cr      = (const float*)d_in[5];
  const float* W1      = (const float*)d_in[6];
  const float* b1      = (const float*)d_in[7];
  const float* W2      = (const float*)d_in[8];
  const float* b2      = (const float*)d_in[9];
  const float* log_eps = (const float*)d_in[10];

  float* out  = (float*)d_out;
  float* sim  = out;                 // [256]
  float* Tm   = out + 256;           // [256][128][128]
  float* Cm   = Tm + 4194304;        // [256][128][128]
  float* cost = Cm + 4194304;        // [256]

  char* ws = (char*)d_ws;
  size_t off = 0;
  auto alloc = [&](size_t bytes)->void*{ void* p = ws + off; off += (bytes+255)&~(size_t)255; return p; };
  u16*   PQ  = (u16*)  alloc(67108864);   // P bf16 (65536x512); later loop planes
  u16*   HQ  = (u16*)  alloc(67108864);   // hidden H bf16 (65536x512)
  u16*   W1T = (u16*)  alloc(524288);
  u16*   W2T = (u16*)  alloc(524288);
  float* NP4 = (float*)alloc(1048576);    // per-cb row-norm partials [4][65536]
  float* LMU = (float*)alloc(131072);
  float* LNU = (float*)alloc(131072);
  float* MUA = (float*)alloc(131072);
  float* NUA = (float*)alloc(131072);
  (void)ws_size; (void)in_sizes; (void)n_in; (void)out_size;

  char* SQHL = (char*)PQ;                  // 16MB bf16 hi/lo Sq planes
  char* SRHL = (char*)PQ + 16777216;       // 16MB bf16 hi/lo Sr planes

  prologue_k<<<2176,256,0,stream>>>(W1, W2, W1T, W2T, mask_q, mask_r,
                                    LMU, LNU, MUA, NUA);
  gemm_k<1,0,1><<<1024,512,0,stream>>>(nullptr, sq, sr, W1T, b1, HQ, nullptr);
  gemm_k<0,1,0><<<1024,512,0,stream>>>(HQ, nullptr, nullptr, W2T, b2, PQ, NP4);
  pdist_all_k<<<768,256,0,stream>>>(PQ, NP4, cq, cr, Cm, SQHL, SRHL);
  fgw_loop_k<<<256,512,0,stream>>>(SQHL, SRHL, Cm, MUA, NUA, LMU, LNU,
                                   log_eps, Tm, cost, sim);
}